// Round 5
// baseline (6147.274 us; speedup 1.0000x reference)
//
#include <hip/hip_runtime.h>

#define NN 1024
#define CC 64
#define BB 2

typedef unsigned long long ull;
typedef unsigned int u32;

__device__ __forceinline__ float wsum(float v){
  #pragma unroll
  for (int o=32;o;o>>=1) v += __shfl_xor(v,o);
  return v;
}
__device__ __forceinline__ float wmaxr(float v){
  #pragma unroll
  for (int o=32;o;o>>=1) v = fmaxf(v, __shfl_xor(v,o));
  return v;
}
__device__ __forceinline__ float wminr(float v){
  #pragma unroll
  for (int o=32;o;o>>=1) v = fminf(v, __shfl_xor(v,o));
  return v;
}
__device__ __forceinline__ ull wmaxu64(ull v){
  #pragma unroll
  for (int o=32;o;o>>=1){ ull x = __shfl_xor(v,o); v = (x>v)?x:v; }
  return v;
}
__device__ __forceinline__ float4 ld4(const float* p){ return *reinterpret_cast<const float4*>(p); }
__device__ __forceinline__ u32 monob(float d){
  u32 u = __float_as_uint(d);
  return (u & 0x80000000u) ? ~u : (u | 0x80000000u);
}

// fmaf-pinned column GEMM — MUST stay value-identical between ksel and kapp.
template<int R>
__device__ __forceinline__ void gemm_cols(const float* __restrict__ col,
                                          const float (*yl)[64], int j4, float (*ad)[4]){
  #pragma unroll
  for (int cc=0; cc<16; cc++){
    float4 c0 = ld4(col + (size_t)(cc*4+0)*NN + j4);
    float4 c1 = ld4(col + (size_t)(cc*4+1)*NN + j4);
    float4 c2 = ld4(col + (size_t)(cc*4+2)*NN + j4);
    float4 c3 = ld4(col + (size_t)(cc*4+3)*NN + j4);
    #pragma unroll
    for (int rr=0; rr<R; rr++){
      float4 y4 = *reinterpret_cast<const float4*>(&yl[rr][cc*4]);
      float a0 = ad[rr][0], a1 = ad[rr][1], a2 = ad[rr][2], a3 = ad[rr][3];
      a0 = fmaf(y4.x,c0.x,a0); a0 = fmaf(y4.y,c1.x,a0); a0 = fmaf(y4.z,c2.x,a0); a0 = fmaf(y4.w,c3.x,a0);
      a1 = fmaf(y4.x,c0.y,a1); a1 = fmaf(y4.y,c1.y,a1); a1 = fmaf(y4.z,c2.y,a1); a1 = fmaf(y4.w,c3.y,a1);
      a2 = fmaf(y4.x,c0.z,a2); a2 = fmaf(y4.y,c1.z,a2); a2 = fmaf(y4.z,c2.z,a2); a2 = fmaf(y4.w,c3.z,a2);
      a3 = fmaf(y4.x,c0.w,a3); a3 = fmaf(y4.y,c1.w,a3); a3 = fmaf(y4.z,c2.w,a3); a3 = fmaf(y4.w,c3.w,a3);
      ad[rr][0]=a0; ad[rr][1]=a1; ad[rr][2]=a2; ad[rr][3]=a3;
    }
  }
}
// D epilogue — identical value chain in both kernels.
__device__ __forceinline__ void dfinish(bool euc, float yn2r, const float4& cn2,
                                        const float ad[4], float dv[4]){
  if (euc){
    dv[0] = sqrtf(fmaxf(fmaf(-2.0f, ad[0], yn2r + cn2.x), 1e-12f));
    dv[1] = sqrtf(fmaxf(fmaf(-2.0f, ad[1], yn2r + cn2.y), 1e-12f));
    dv[2] = sqrtf(fmaxf(fmaf(-2.0f, ad[2], yn2r + cn2.z), 1e-12f));
    dv[3] = sqrtf(fmaxf(fmaf(-2.0f, ad[3], yn2r + cn2.w), 1e-12f));
  } else {
    dv[0] = 1.0f - ad[0]; dv[1] = 1.0f - ad[1];
    dv[2] = 1.0f - ad[2]; dv[3] = 1.0f - ad[3];
  }
}

// ---------------- zero init ----------------
__global__ void kz(float* __restrict__ out, double* __restrict__ sums){
  int i = blockIdx.x*256 + threadIdx.x;
  if (i < BB*CC*NN) out[i] = 0.0f;
  if (i < 36) sums[i] = 0.0;
}

// ---------------- K0a: transpose x[b][c][n] -> f[s][b][n][c] ----------------
__global__ __launch_bounds__(256)
void k0a(const float* __restrict__ x1, const float* __restrict__ x2, const float* __restrict__ x3,
         float* __restrict__ f){
  int bid = blockIdx.x;
  int tile = bid & 15;
  int b = (bid >> 4) & 1;
  int s = bid >> 5;
  const float* x = (s==0)?x1:((s==1)?x2:x3);
  __shared__ float lds[64][65];
  int i0 = tile*64;
  for (int idx = threadIdx.x; idx < 4096; idx += 256){
    int c = idx >> 6, ii = idx & 63;
    lds[c][ii] = x[(size_t)(b*CC + c)*NN + i0 + ii];
  }
  __syncthreads();
  for (int idx = threadIdx.x; idx < 4096; idx += 256){
    int ii = idx >> 6, c = idx & 63;
    f[((size_t)(s*BB + b)*NN + i0 + ii)*CC + c] = lds[c][ii];
  }
}

// ---------------- K0b: norms, fnT, p, pT ----------------
__global__ __launch_bounds__(256)
void k0b(const float* __restrict__ f,
         const float* __restrict__ w1, const float* __restrict__ b1,
         const float* __restrict__ w2, const float* __restrict__ b2,
         const float* __restrict__ w3, const float* __restrict__ b3,
         float* __restrict__ p, float* __restrict__ pT,
         float* __restrict__ fnT, float* __restrict__ nrm2g){
  int bid = blockIdx.x;
  int chunk = bid & 63;
  int b = (bid >> 6) & 1;
  int s = bid >> 7;
  const float* w = (s==0)?w1:((s==1)?w2:w3);
  const float* bias = (s==0)?b1:((s==1)?b2:b3);
  __shared__ float wl[64][65];
  __shared__ float fr[16][65];
  __shared__ float n2[16];
  int i0 = chunk*16;
  int t = threadIdx.x;
  for (int idx = t; idx < 4096; idx += 256){
    int o = idx >> 6, c = idx & 63;
    wl[o][c] = w[idx];
  }
  for (int idx = t; idx < 1024; idx += 256){
    int rr = idx >> 6, c = idx & 63;
    fr[rr][c] = f[((size_t)(s*BB + b)*NN + i0 + rr)*CC + c];
  }
  __syncthreads();
  {
    int r = t >> 4, l = t & 15;
    float pv = 0.f;
    for (int c = l; c < 64; c += 16) pv += fr[r][c]*fr[r][c];
    #pragma unroll
    for (int o=8;o;o>>=1) pv += __shfl_down(pv, o, 16);
    if (l == 0) n2[r] = pv;
  }
  __syncthreads();
  if (t < 16) nrm2g[(size_t)(s*BB + b)*NN + i0 + t] = n2[t];
  for (int idx = t; idx < 1024; idx += 256){
    int rr = idx >> 6, c = idx & 63;
    float rinv = 1.0f / fmaxf(sqrtf(n2[rr]), 1e-12f);
    fnT[((size_t)(s*BB + b)*CC + c)*NN + i0 + rr] = fr[rr][c]*rinv;
  }
  for (int idx = t; idx < 1024; idx += 256){
    int rr = idx >> 6, o = idx & 63;
    float acc = bias[o];
    #pragma unroll
    for (int c = 0; c < 64; c++) acc += fr[rr][c]*wl[o][c];
    p [((size_t)(s*BB + b)*NN + i0 + rr)*CC + o] = acc;
    pT[((size_t)(s*BB + b)*CC + o)*NN + i0 + rr] = acc;
  }
}

// ---------------- K2: mu + alpha*sigma ----------------
__global__ void k2(const double* __restrict__ sums, float* __restrict__ baseg){
  int t = threadIdx.x;
  if (t < 18){
    double S = sums[t*2], S2 = sums[t*2+1];
    const double Nsq = 1048576.0;
    double mu = S / Nsq;
    double var = (S2 - S*S/Nsq) / (Nsq - 1.0);
    double sg = var > 0.0 ? sqrt(var) : 0.0;
    baseg[t] = (float)(mu + 0.08*sg);
  }
}

// ---------------- ksel: D-GEMM + stats + per-row selection boundary ----------------
// rec[m*NN+i] = {dB_bits, jB, Dmax_bits, decay_bits}; selected(j) <=> (bits<dB)||(bits==dB && j<=jB)
__global__ __launch_bounds__(256, 2)
void ksel(const float* __restrict__ x1, const float* __restrict__ x2, const float* __restrict__ x3,
          const float* __restrict__ f, const float* __restrict__ fnT,
          const float* __restrict__ nrm2g, double* __restrict__ sums, uint4* __restrict__ rec){
  __shared__ __align__(16) float yl[16][64];     // 4KB
  __shared__ __align__(16) float Dt[16][NN];     // 64KB
  __shared__ float hist[4][256];                 // 4KB
  __shared__ float candd[4][64];
  __shared__ int   candj[4][64];
  __shared__ u32   candb[4][64];
  __shared__ float yn2[16];
  __shared__ int   cnt4[4];
  __shared__ int   selI4[4];
  __shared__ float selC4[4];
  __shared__ float s1s[4], s2s[4];

  int bid = blockIdx.x;
  int tile = bid & 63;             // 64 tiles of 16 rows
  int q = (bid >> 6) % 9;
  int b = bid / 576;
  int r = q / 3, s = q - 3*r;
  bool euc = (r == s);
  int m = b*9 + q;
  int i0 = tile*16;
  int t = threadIdx.x;
  int w = t >> 6, lane = t & 63;

  if (t < 16) yn2[t] = nrm2g[(size_t)(r*BB + b)*NN + i0 + t];
  __syncthreads();
  for (int idx = t; idx < 1024; idx += 256){
    int rr = idx >> 6, c = idx & 63;
    float v = f[((size_t)(r*BB + b)*NN + i0 + rr)*CC + c];
    if (!euc) v *= 1.0f / fmaxf(sqrtf(yn2[rr]), 1e-12f);
    yl[rr][c] = v;
  }
  __syncthreads();

  const float* xs = (s==0)?x1:((s==1)?x2:x3);
  const float* colD = euc ? (xs + (size_t)(b*CC)*NN) : (fnT + (size_t)((s*BB + b)*CC)*NN);
  int j4 = 4*t;

  float ad[16][4];
  #pragma unroll
  for (int rr=0;rr<16;rr++){ ad[rr][0]=0.f; ad[rr][1]=0.f; ad[rr][2]=0.f; ad[rr][3]=0.f; }
  gemm_cols<16>(colD, yl, j4, ad);

  float4 cn2 = make_float4(0.f,0.f,0.f,0.f);
  if (euc) cn2 = ld4(nrm2g + (size_t)(s*BB + b)*NN + j4);

  float sd = 0.f, sd2 = 0.f;
  #pragma unroll
  for (int rr=0;rr<16;rr++){
    float dv[4];
    dfinish(euc, yn2[rr], cn2, ad[rr], dv);
    sd  += dv[0]+dv[1]+dv[2]+dv[3];
    sd2 += dv[0]*dv[0]+dv[1]*dv[1]+dv[2]*dv[2]+dv[3]*dv[3];
    float4 o4; o4.x=dv[0]; o4.y=dv[1]; o4.z=dv[2]; o4.w=dv[3];
    *reinterpret_cast<float4*>(&Dt[rr][j4]) = o4;
  }
  sd = wsum(sd); sd2 = wsum(sd2);
  if (lane == 0){ s1s[w] = sd; s2s[w] = sd2; }
  __syncthreads();
  if (t == 0){
    double S  = (double)s1s[0] + (double)s1s[1] + (double)s1s[2] + (double)s1s[3];
    double S2 = (double)s2s[0] + (double)s2s[1] + (double)s2s[2] + (double)s2s[3];
    atomicAdd(&sums[m*2 + 0], S);
    atomicAdd(&sums[m*2 + 1], S2);
  }

  // ---- per-wave selection: wave w handles rows 4w..4w+3 ----
  for (int rr2 = 0; rr2 < 4; rr2++){
    int row = w*4 + rr2;
    float dreg[16];
    #pragma unroll
    for (int k2=0;k2<4;k2++){
      float4 v = ld4(&Dt[row][4*lane + 256*k2]);
      dreg[4*k2+0]=v.x; dreg[4*k2+1]=v.y; dreg[4*k2+2]=v.z; dreg[4*k2+3]=v.w;
    }
    float lmin = 3.4e38f, lmax = -3.4e38f;
    #pragma unroll
    for (int k=0;k<16;k++){ lmin = fminf(lmin,dreg[k]); lmax = fmaxf(lmax,dreg[k]); }
    float Dmin = wminr(lmin);
    float Dmax = wmaxr(lmax);
    float lz = 0.f;
    #pragma unroll
    for (int k=0;k<16;k++) lz += expf((Dmin - dreg[k])*0.1f);
    float Z = wsum(lz);
    float invZ = 1.0f/Z;
    float preg[16];
    #pragma unroll
    for (int k=0;k<16;k++) preg[k] = expf((Dmin - dreg[k])*0.1f)*invZ;
    float le = 0.f;
    #pragma unroll
    for (int k=0;k<16;k++) le += preg[k]*logf(preg[k] + 1e-8f);
    float ent = -wsum(le);
    float decay = expf(-ent);
    float range = Dmax - Dmin;
    float scale1 = 256.0f / fmaxf(range, 1e-30f);

    if (lane==0){ selI4[w]=255; selC4[w]=0.8f; cnt4[w]=0; }
    #pragma unroll
    for (int i=0;i<4;i++) hist[w][lane*4+i] = 0.f;
    __syncthreads();
    #pragma unroll
    for (int k=0;k<16;k++){
      int b1 = (int)((dreg[k]-Dmin)*scale1); b1 = (b1>255)?255:b1;
      atomicAdd(&hist[w][b1], preg[k]);
    }
    __syncthreads();
    {
      float h0=hist[w][lane*4+0], h1=hist[w][lane*4+1], h2=hist[w][lane*4+2], h3=hist[w][lane*4+3];
      float tot = h0+h1+h2+h3;
      float incl = tot;
      #pragma unroll
      for (int o=1;o<64;o<<=1){ float v = __shfl_up(incl,o); if (lane>=o) incl += v; }
      float excl = incl - tot;
      float c0=excl, c1=excl+h0, c2=c1+h1, c3=c2+h2;
      bool f0=(c0<=0.8f && 0.8f<c0+h0), f1=(c1<=0.8f && 0.8f<c1+h1),
           f2=(c2<=0.8f && 0.8f<c2+h2), f3=(c3<=0.8f && 0.8f<c3+h3);
      if (f0){ selI4[w]=lane*4+0; selC4[w]=c0; }
      if (f1){ selI4[w]=lane*4+1; selC4[w]=c1; }
      if (f2){ selI4[w]=lane*4+2; selC4[w]=c2; }
      if (f3){ selI4[w]=lane*4+3; selC4[w]=c3; }
      if (__ballot(f0||f1||f2||f3) == 0ull){   // crack fallback
        int bi = 10000; float bc = 0.f;
        if (c0>0.8f){bi=lane*4+0;bc=c0;} else if (c1>0.8f){bi=lane*4+1;bc=c1;}
        else if (c2>0.8f){bi=lane*4+2;bc=c2;} else if (c3>0.8f){bi=lane*4+3;bc=c3;}
        int mn = bi;
        #pragma unroll
        for (int o=32;o;o>>=1) mn = min(mn, __shfl_xor(mn,o));
        if (mn==bi && bi<10000){ selI4[w]=bi; selC4[w]=bc; }
      }
    }
    __syncthreads();
    int B1 = selI4[w]; float cb1 = selC4[w];
    float lo2 = Dmin + (float)B1/scale1;
    float scale2 = scale1*256.0f;
    if (lane==0){ selI4[w]=255; selC4[w]=cb1; }
    #pragma unroll
    for (int i=0;i<4;i++) hist[w][lane*4+i] = 0.f;
    __syncthreads();
    #pragma unroll
    for (int k=0;k<16;k++){
      int b1 = (int)((dreg[k]-Dmin)*scale1); b1 = (b1>255)?255:b1;
      if (b1 == B1){
        int b2 = (int)((dreg[k]-lo2)*scale2); b2 = (b2<0)?0:((b2>255)?255:b2);
        atomicAdd(&hist[w][b2], preg[k]);
      }
    }
    __syncthreads();
    {
      float h0=hist[w][lane*4+0], h1=hist[w][lane*4+1], h2=hist[w][lane*4+2], h3=hist[w][lane*4+3];
      float tot = h0+h1+h2+h3;
      float incl = tot;
      #pragma unroll
      for (int o=1;o<64;o<<=1){ float v = __shfl_up(incl,o); if (lane>=o) incl += v; }
      float excl = incl - tot;
      float c0=cb1+excl, c1=c0+h0, c2=c1+h1, c3=c2+h2;
      bool f0=(c0<=0.8f && 0.8f<c0+h0), f1=(c1<=0.8f && 0.8f<c1+h1),
           f2=(c2<=0.8f && 0.8f<c2+h2), f3=(c3<=0.8f && 0.8f<c3+h3);
      if (f0){ selI4[w]=lane*4+0; selC4[w]=c0; }
      if (f1){ selI4[w]=lane*4+1; selC4[w]=c1; }
      if (f2){ selI4[w]=lane*4+2; selC4[w]=c2; }
      if (f3){ selI4[w]=lane*4+3; selC4[w]=c3; }
      if (__ballot(f0||f1||f2||f3) == 0ull){
        int bi = 10000; float bc = 0.f;
        if (c0>0.8f){bi=lane*4+0;bc=c0;} else if (c1>0.8f){bi=lane*4+1;bc=c1;}
        else if (c2>0.8f){bi=lane*4+2;bc=c2;} else if (c3>0.8f){bi=lane*4+3;bc=c3;}
        int mn = bi;
        #pragma unroll
        for (int o=32;o;o>>=1) mn = min(mn, __shfl_xor(mn,o));
        if (mn==bi && bi<10000){ selI4[w]=bi; selC4[w]=bc; }
      }
    }
    __syncthreads();
    int B2 = selI4[w]; float cb2 = selC4[w];

    // candidates in (B1,B2)
    #pragma unroll
    for (int k=0;k<16;k++){
      int b1 = (int)((dreg[k]-Dmin)*scale1); b1 = (b1>255)?255:b1;
      if (b1 == B1){
        int b2 = (int)((dreg[k]-lo2)*scale2); b2 = (b2<0)?0:((b2>255)?255:b2);
        if (b2 == B2){
          int c = atomicAdd(&cnt4[w], 1);
          if (c < 64){
            int j = (k>>2)*256 + 4*lane + (k&3);
            candj[w][c] = j;
            candd[w][c] = dreg[k];
            candb[w][c] = monob(dreg[k]);
          }
        }
      }
    }
    __syncthreads();
    // lex-max element strictly before sub-bucket (B1,B2) — all selected
    ull em = 0;
    #pragma unroll
    for (int k=0;k<16;k++){
      int b1 = (int)((dreg[k]-Dmin)*scale1); b1 = (b1>255)?255:b1;
      bool qual;
      if (b1 < B1) qual = true;
      else if (b1 > B1) qual = false;
      else {
        int b2 = (int)((dreg[k]-lo2)*scale2); b2 = (b2<0)?0:((b2>255)?255:b2);
        qual = (b2 < B2);
      }
      if (qual){
        int j = (k>>2)*256 + 4*lane + (k&3);
        ull key = ((ull)monob(dreg[k]) << 32) | (u32)j;
        if (key > em) em = key;
      }
    }
    em = wmaxu64(em);
    if (lane == 0){
      int n = cnt4[w]; n = (n>64)?64:n;
      ull best = em;
      for (int a=0;a<n;a++){
        float da = candd[w][a]; int ja = candj[w][a];
        float acc = cb2;
        for (int bb=0;bb<n;bb++){
          float db = candd[w][bb]; int jb = candj[w][bb];
          if (db < da || (db == da && jb <= ja))
            acc += expf((Dmin - db)*0.1f)*invZ;
        }
        if (acc <= 0.8f){
          ull key = ((ull)candb[w][a] << 32) | (u32)ja;
          if (key > best) best = key;
        }
      }
      rec[(size_t)m*NN + i0 + row] = make_uint4((u32)(best>>32), (u32)(best & 0xFFFFFFFFu),
                                               __float_as_uint(Dmax), __float_as_uint(decay));
    }
    __syncthreads();
  }
}

// ---------------- kapp: fused D+S GEMM + mask + softmax + o-accum ----------------
__global__ __launch_bounds__(256, 3)
void kapp(const float* __restrict__ x1, const float* __restrict__ x2, const float* __restrict__ x3,
          const float* __restrict__ f, const float* __restrict__ p,
          const float* __restrict__ fnT, const float* __restrict__ pT,
          const float* __restrict__ nrm2g, const float* __restrict__ baseg,
          const uint4* __restrict__ rec, float* __restrict__ out){
  __shared__ __align__(16) float yl[8][64];
  __shared__ __align__(16) float pyl[8][64];
  __shared__ __align__(16) float Sm[8][NN];        // 32KB
  __shared__ __align__(16) float opart[4][8][64];  // 8KB
  __shared__ float yn2[8];
  __shared__ u32 dBb[8]; __shared__ u32 jBl[8];
  __shared__ float th[8];

  int bid = blockIdx.x;
  int tile = bid & 127;            // 128 tiles of 8 rows
  int q = (bid >> 7) % 9;
  int b = bid / 1152;
  int r = q / 3, s = q - 3*r;
  bool euc = (r == s);
  int m = b*9 + q;
  int i0 = tile*8;
  int t = threadIdx.x;
  int w = t >> 6, lane = t & 63;

  if (t < 8){
    yn2[t] = nrm2g[(size_t)(r*BB + b)*NN + i0 + t];
    uint4 R = rec[(size_t)m*NN + i0 + t];
    dBb[t] = R.x; jBl[t] = R.y;
    float Dmax = __uint_as_float(R.z);
    float decay = __uint_as_float(R.w);
    float Tb = baseg[m];
    th[t] = (Tb + 0.01f*decay) / (1.0f + 0.01f*decay/Dmax);
  }
  __syncthreads();
  for (int idx = t; idx < 512; idx += 256){
    int rr = idx >> 6, c = idx & 63;
    float v = f[((size_t)(r*BB + b)*NN + i0 + rr)*CC + c];
    if (!euc) v *= 1.0f / fmaxf(sqrtf(yn2[rr]), 1e-12f);
    yl[rr][c] = v;
    pyl[rr][c] = p[((size_t)(r*BB + b)*NN + i0 + rr)*CC + c];
  }
  __syncthreads();

  const float* xs = (s==0)?x1:((s==1)?x2:x3);
  const float* colD = euc ? (xs + (size_t)(b*CC)*NN) : (fnT + (size_t)((s*BB + b)*CC)*NN);
  const float* colP = pT + (size_t)((s*BB + b)*CC)*NN;
  int j4 = 4*t;

  float ad[8][4], ap[8][4];
  #pragma unroll
  for (int rr=0;rr<8;rr++){
    ad[rr][0]=0.f; ad[rr][1]=0.f; ad[rr][2]=0.f; ad[rr][3]=0.f;
    ap[rr][0]=0.f; ap[rr][1]=0.f; ap[rr][2]=0.f; ap[rr][3]=0.f;
  }
  gemm_cols<8>(colD, yl, j4, ad);
  gemm_cols<8>(colP, pyl, j4, ap);

  float4 cn2 = make_float4(0.f,0.f,0.f,0.f);
  if (euc) cn2 = ld4(nrm2g + (size_t)(s*BB + b)*NN + j4);

  #pragma unroll
  for (int rr=0;rr<8;rr++){
    float dv[4];
    dfinish(euc, yn2[rr], cn2, ad[rr], dv);
    u32 db = dBb[rr]; u32 jb = jBl[rr]; float tt = th[rr];
    float4 sv;
    {
      u32 bits = monob(dv[0]); u32 j = (u32)(j4+0);
      bool sel = (bits < db) || (bits == db && j <= jb);
      sv.x = (sel && dv[0] < tt) ? ap[rr][0] : 0.f;
    }
    {
      u32 bits = monob(dv[1]); u32 j = (u32)(j4+1);
      bool sel = (bits < db) || (bits == db && j <= jb);
      sv.y = (sel && dv[1] < tt) ? ap[rr][1] : 0.f;
    }
    {
      u32 bits = monob(dv[2]); u32 j = (u32)(j4+2);
      bool sel = (bits < db) || (bits == db && j <= jb);
      sv.z = (sel && dv[2] < tt) ? ap[rr][2] : 0.f;
    }
    {
      u32 bits = monob(dv[3]); u32 j = (u32)(j4+3);
      bool sel = (bits < db) || (bits == db && j <= jb);
      sv.w = (sel && dv[3] < tt) ? ap[rr][3] : 0.f;
    }
    *reinterpret_cast<float4*>(&Sm[rr][j4]) = sv;
  }
  __syncthreads();

  // row softmax: wave w owns rows 2w, 2w+1
  #pragma unroll
  for (int e=0;e<2;e++){
    int row = 2*w + e;
    float s16[16];
    #pragma unroll
    for (int k2=0;k2<4;k2++){
      float4 v = ld4(&Sm[row][4*lane + 256*k2]);
      s16[4*k2+0]=v.x; s16[4*k2+1]=v.y; s16[4*k2+2]=v.z; s16[4*k2+3]=v.w;
    }
    float lm = -3.4e38f;
    #pragma unroll
    for (int k=0;k<16;k++) lm = fmaxf(lm, s16[k]);
    float M = wmaxr(lm);
    float ls = 0.f;
    #pragma unroll
    for (int k=0;k<16;k++) ls += expf(s16[k]-M);
    float Z2 = wsum(ls);
    float iZ2 = 1.0f/Z2;
    #pragma unroll
    for (int k2=0;k2<4;k2++){
      float4 v;
      v.x = expf(s16[4*k2+0]-M)*iZ2;
      v.y = expf(s16[4*k2+1]-M)*iZ2;
      v.z = expf(s16[4*k2+2]-M)*iZ2;
      v.w = expf(s16[4*k2+3]-M)*iZ2;
      *reinterpret_cast<float4*>(&Sm[row][4*lane + 256*k2]) = v;
    }
  }
  __syncthreads();

  // o-accum: thread (cg = t&15 channel-quad, jj = t>>4), j = jj + 16*mm
  int cg = t & 15, jj = t >> 4;
  float acc[8][4];
  #pragma unroll
  for (int rr=0;rr<8;rr++){ acc[rr][0]=0.f; acc[rr][1]=0.f; acc[rr][2]=0.f; acc[rr][3]=0.f; }
  const float* fs = f + (size_t)((s*BB + b)*NN)*CC;
  for (int mm=0; mm<64; mm++){
    int j = jj + 16*mm;
    float4 fv = ld4(&fs[(size_t)j*CC + 4*cg]);
    #pragma unroll
    for (int rr=0;rr<8;rr++){
      float pv = Sm[rr][j];
      acc[rr][0] = fmaf(pv, fv.x, acc[rr][0]);
      acc[rr][1] = fmaf(pv, fv.y, acc[rr][1]);
      acc[rr][2] = fmaf(pv, fv.z, acc[rr][2]);
      acc[rr][3] = fmaf(pv, fv.w, acc[rr][3]);
    }
  }
  #pragma unroll
  for (int rr=0;rr<8;rr++){
    #pragma unroll
    for (int i=0;i<4;i++){
      acc[rr][i] += __shfl_xor(acc[rr][i], 16);
      acc[rr][i] += __shfl_xor(acc[rr][i], 32);
    }
  }
  if (lane < 16){
    #pragma unroll
    for (int rr=0;rr<8;rr++){
      float4 v; v.x=acc[rr][0]; v.y=acc[rr][1]; v.z=acc[rr][2]; v.w=acc[rr][3];
      *reinterpret_cast<float4*>(&opart[w][rr][4*cg]) = v;
    }
  }
  __syncthreads();
  #pragma unroll
  for (int e=0;e<2;e++){
    int idx = t + 256*e;
    int rr = idx >> 6, c = idx & 63;
    float v = opart[0][rr][c]+opart[1][rr][c]+opart[2][rr][c]+opart[3][rr][c];
    atomicAdd(&out[(size_t)(b*CC + c)*NN + i0 + rr], v);
  }
}

extern "C" void kernel_launch(void* const* d_in, const int* in_sizes, int n_in,
                              void* d_out, int out_size, void* d_ws, size_t ws_size,
                              hipStream_t stream){
  const float* x1 = (const float*)d_in[0];
  const float* x2 = (const float*)d_in[1];
  const float* x3 = (const float*)d_in[2];
  const float* w1 = (const float*)d_in[3];
  const float* b1 = (const float*)d_in[4];
  const float* w2 = (const float*)d_in[5];
  const float* b2 = (const float*)d_in[6];
  const float* w3 = (const float*)d_in[7];
  const float* b3 = (const float*)d_in[8];

  char* ws = (char*)d_ws;
  const size_t SZ = (size_t)3*BB*NN*CC*sizeof(float);   // 1.5MB each
  float*  f    = (float*)(ws);
  float*  p    = (float*)(ws + SZ);
  float*  fnT  = (float*)(ws + 2*SZ);
  float*  pT   = (float*)(ws + 3*SZ);
  float*  nrm2 = (float*)(ws + 4*SZ);
  double* sums = (double*)(ws + 4*SZ + 32768);
  float*  baseg= (float*)(ws + 4*SZ + 32768 + 512);
  uint4*  rec  = (uint4*)(ws + 4*SZ + 65536);           // 18*1024*16B = 288KB

  float* out = (float*)d_out;

  kz  <<<512, 256, 0, stream>>>(out, sums);
  k0a <<<96,  256, 0, stream>>>(x1, x2, x3, f);
  k0b <<<384, 256, 0, stream>>>(f, w1, b1, w2, b2, w3, b3, p, pT, fnT, nrm2);
  ksel<<<1152,256, 0, stream>>>(x1, x2, x3, f, fnT, nrm2, sums, rec);
  k2  <<<1,   64,  0, stream>>>(sums, baseg);
  kapp<<<2304,256, 0, stream>>>(x1, x2, x3, f, p, fnT, pT, nrm2, baseg, rec, out);
}

// Round 6
// 5477.503 us; speedup vs baseline: 1.1223x; 1.1223x over previous
//
#include <hip/hip_runtime.h>

#define NN 1024
#define CC 64
#define BB 2

typedef unsigned long long ull;
typedef unsigned int u32;

__device__ __forceinline__ float wsum(float v){
  #pragma unroll
  for (int o=32;o;o>>=1) v += __shfl_xor(v,o);
  return v;
}
__device__ __forceinline__ float wmaxr(float v){
  #pragma unroll
  for (int o=32;o;o>>=1) v = fmaxf(v, __shfl_xor(v,o));
  return v;
}
__device__ __forceinline__ float wminr(float v){
  #pragma unroll
  for (int o=32;o;o>>=1) v = fminf(v, __shfl_xor(v,o));
  return v;
}
__device__ __forceinline__ ull wmaxu64(ull v){
  #pragma unroll
  for (int o=32;o;o>>=1){ ull x = __shfl_xor(v,o); v = (x>v)?x:v; }
  return v;
}
__device__ __forceinline__ float4 ld4(const float* p){ return *reinterpret_cast<const float4*>(p); }
__device__ __forceinline__ u32 monob(float d){
  u32 u = __float_as_uint(d);
  return (u & 0x80000000u) ? ~u : (u | 0x80000000u);
}

// GEMM inner loop as a MACRO: accumulator array stays a kernel-scope local with
// static indexing -> SROA keeps it in VGPRs (R5's pointer-arg version spilled to
// scratch: 16.7GB HBM traffic, VALUBusy 2%). Identical text in ksel & kapp keeps
// the fmaf chain bitwise-identical so the exact d==dB boundary test stays valid.
#define GEMM_COLS(R, col, ylm, j4v, adv)                                          \
  { _Pragma("unroll")                                                             \
    for (int cc=0; cc<16; cc++){                                                  \
      float4 c0 = ld4((col) + (size_t)(cc*4+0)*NN + (j4v));                       \
      float4 c1 = ld4((col) + (size_t)(cc*4+1)*NN + (j4v));                       \
      float4 c2 = ld4((col) + (size_t)(cc*4+2)*NN + (j4v));                       \
      float4 c3 = ld4((col) + (size_t)(cc*4+3)*NN + (j4v));                       \
      _Pragma("unroll")                                                           \
      for (int rr=0; rr<(R); rr++){                                               \
        float4 y4 = *reinterpret_cast<const float4*>(&(ylm)[rr][cc*4]);           \
        float a0 = adv[rr][0], a1 = adv[rr][1], a2 = adv[rr][2], a3 = adv[rr][3]; \
        a0 = fmaf(y4.x,c0.x,a0); a0 = fmaf(y4.y,c1.x,a0); a0 = fmaf(y4.z,c2.x,a0); a0 = fmaf(y4.w,c3.x,a0); \
        a1 = fmaf(y4.x,c0.y,a1); a1 = fmaf(y4.y,c1.y,a1); a1 = fmaf(y4.z,c2.y,a1); a1 = fmaf(y4.w,c3.y,a1); \
        a2 = fmaf(y4.x,c0.z,a2); a2 = fmaf(y4.y,c1.z,a2); a2 = fmaf(y4.z,c2.z,a2); a2 = fmaf(y4.w,c3.z,a2); \
        a3 = fmaf(y4.x,c0.w,a3); a3 = fmaf(y4.y,c1.w,a3); a3 = fmaf(y4.z,c2.w,a3); a3 = fmaf(y4.w,c3.w,a3); \
        adv[rr][0]=a0; adv[rr][1]=a1; adv[rr][2]=a2; adv[rr][3]=a3;               \
      }                                                                           \
    }                                                                             \
  }

// D epilogue macro — identical value chain in both kernels.
#define DFINISH(eucv, yn2r, cn2v, adr, dvv)                                       \
  { if (eucv){                                                                    \
      dvv[0] = sqrtf(fmaxf(fmaf(-2.0f, adr[0], (yn2r) + (cn2v).x), 1e-12f));      \
      dvv[1] = sqrtf(fmaxf(fmaf(-2.0f, adr[1], (yn2r) + (cn2v).y), 1e-12f));      \
      dvv[2] = sqrtf(fmaxf(fmaf(-2.0f, adr[2], (yn2r) + (cn2v).z), 1e-12f));      \
      dvv[3] = sqrtf(fmaxf(fmaf(-2.0f, adr[3], (yn2r) + (cn2v).w), 1e-12f));      \
    } else {                                                                      \
      dvv[0] = 1.0f - adr[0]; dvv[1] = 1.0f - adr[1];                             \
      dvv[2] = 1.0f - adr[2]; dvv[3] = 1.0f - adr[3];                             \
    }                                                                             \
  }

// ---------------- zero init ----------------
__global__ void kz(float* __restrict__ out, double* __restrict__ sums){
  int i = blockIdx.x*256 + threadIdx.x;
  if (i < BB*CC*NN) out[i] = 0.0f;
  if (i < 36) sums[i] = 0.0;
}

// ---------------- K0a: transpose x[b][c][n] -> f[s][b][n][c] ----------------
__global__ __launch_bounds__(256)
void k0a(const float* __restrict__ x1, const float* __restrict__ x2, const float* __restrict__ x3,
         float* __restrict__ f){
  int bid = blockIdx.x;
  int tile = bid & 15;
  int b = (bid >> 4) & 1;
  int s = bid >> 5;
  const float* x = (s==0)?x1:((s==1)?x2:x3);
  __shared__ float lds[64][65];
  int i0 = tile*64;
  for (int idx = threadIdx.x; idx < 4096; idx += 256){
    int c = idx >> 6, ii = idx & 63;
    lds[c][ii] = x[(size_t)(b*CC + c)*NN + i0 + ii];
  }
  __syncthreads();
  for (int idx = threadIdx.x; idx < 4096; idx += 256){
    int ii = idx >> 6, c = idx & 63;
    f[((size_t)(s*BB + b)*NN + i0 + ii)*CC + c] = lds[c][ii];
  }
}

// ---------------- K0b: norms, fnT, p, pT ----------------
__global__ __launch_bounds__(256)
void k0b(const float* __restrict__ f,
         const float* __restrict__ w1, const float* __restrict__ b1,
         const float* __restrict__ w2, const float* __restrict__ b2,
         const float* __restrict__ w3, const float* __restrict__ b3,
         float* __restrict__ p, float* __restrict__ pT,
         float* __restrict__ fnT, float* __restrict__ nrm2g){
  int bid = blockIdx.x;
  int chunk = bid & 63;
  int b = (bid >> 6) & 1;
  int s = bid >> 7;
  const float* w = (s==0)?w1:((s==1)?w2:w3);
  const float* bias = (s==0)?b1:((s==1)?b2:b3);
  __shared__ float wl[64][65];
  __shared__ float fr[16][65];
  __shared__ float n2[16];
  int i0 = chunk*16;
  int t = threadIdx.x;
  for (int idx = t; idx < 4096; idx += 256){
    int o = idx >> 6, c = idx & 63;
    wl[o][c] = w[idx];
  }
  for (int idx = t; idx < 1024; idx += 256){
    int rr = idx >> 6, c = idx & 63;
    fr[rr][c] = f[((size_t)(s*BB + b)*NN + i0 + rr)*CC + c];
  }
  __syncthreads();
  {
    int r = t >> 4, l = t & 15;
    float pv = 0.f;
    for (int c = l; c < 64; c += 16) pv += fr[r][c]*fr[r][c];
    #pragma unroll
    for (int o=8;o;o>>=1) pv += __shfl_down(pv, o, 16);
    if (l == 0) n2[r] = pv;
  }
  __syncthreads();
  if (t < 16) nrm2g[(size_t)(s*BB + b)*NN + i0 + t] = n2[t];
  for (int idx = t; idx < 1024; idx += 256){
    int rr = idx >> 6, c = idx & 63;
    float rinv = 1.0f / fmaxf(sqrtf(n2[rr]), 1e-12f);
    fnT[((size_t)(s*BB + b)*CC + c)*NN + i0 + rr] = fr[rr][c]*rinv;
  }
  for (int idx = t; idx < 1024; idx += 256){
    int rr = idx >> 6, o = idx & 63;
    float acc = bias[o];
    #pragma unroll
    for (int c = 0; c < 64; c++) acc += fr[rr][c]*wl[o][c];
    p [((size_t)(s*BB + b)*NN + i0 + rr)*CC + o] = acc;
    pT[((size_t)(s*BB + b)*CC + o)*NN + i0 + rr] = acc;
  }
}

// ---------------- K2: mu + alpha*sigma ----------------
__global__ void k2(const double* __restrict__ sums, float* __restrict__ baseg){
  int t = threadIdx.x;
  if (t < 18){
    double S = sums[t*2], S2 = sums[t*2+1];
    const double Nsq = 1048576.0;
    double mu = S / Nsq;
    double var = (S2 - S*S/Nsq) / (Nsq - 1.0);
    double sg = var > 0.0 ? sqrt(var) : 0.0;
    baseg[t] = (float)(mu + 0.08*sg);
  }
}

// ---------------- ksel: D-GEMM + stats + per-row selection boundary ----------------
// rec[m*NN+i] = {dB_bits, jB, Dmax_bits, decay_bits}; selected(j) <=> (bits<dB)||(bits==dB && j<=jB)
__global__ __launch_bounds__(256, 2)
void ksel(const float* __restrict__ x1, const float* __restrict__ x2, const float* __restrict__ x3,
          const float* __restrict__ f, const float* __restrict__ fnT,
          const float* __restrict__ nrm2g, double* __restrict__ sums, uint4* __restrict__ rec){
  __shared__ __align__(16) float yl[16][64];     // 4KB
  __shared__ __align__(16) float Dt[16][NN];     // 64KB
  __shared__ float hist[4][256];                 // 4KB
  __shared__ float candd[4][64];
  __shared__ int   candj[4][64];
  __shared__ u32   candb[4][64];
  __shared__ float yn2[16];
  __shared__ int   cnt4[4];
  __shared__ int   selI4[4];
  __shared__ float selC4[4];
  __shared__ float s1s[4], s2s[4];

  int bid = blockIdx.x;
  int tile = bid & 63;             // 64 tiles of 16 rows
  int q = (bid >> 6) % 9;
  int b = bid / 576;
  int r = q / 3, s = q - 3*r;
  bool euc = (r == s);
  int m = b*9 + q;
  int i0 = tile*16;
  int t = threadIdx.x;
  int w = t >> 6, lane = t & 63;

  if (t < 16) yn2[t] = nrm2g[(size_t)(r*BB + b)*NN + i0 + t];
  __syncthreads();
  for (int idx = t; idx < 1024; idx += 256){
    int rr = idx >> 6, c = idx & 63;
    float v = f[((size_t)(r*BB + b)*NN + i0 + rr)*CC + c];
    if (!euc) v *= 1.0f / fmaxf(sqrtf(yn2[rr]), 1e-12f);
    yl[rr][c] = v;
  }
  __syncthreads();

  const float* xs = (s==0)?x1:((s==1)?x2:x3);
  const float* colD = euc ? (xs + (size_t)(b*CC)*NN) : (fnT + (size_t)((s*BB + b)*CC)*NN);
  int j4 = 4*t;

  float ad[16][4];
  #pragma unroll
  for (int rr=0;rr<16;rr++){ ad[rr][0]=0.f; ad[rr][1]=0.f; ad[rr][2]=0.f; ad[rr][3]=0.f; }
  GEMM_COLS(16, colD, yl, j4, ad)

  float4 cn2 = make_float4(0.f,0.f,0.f,0.f);
  if (euc) cn2 = ld4(nrm2g + (size_t)(s*BB + b)*NN + j4);

  float sd = 0.f, sd2 = 0.f;
  #pragma unroll
  for (int rr=0;rr<16;rr++){
    float dv[4];
    DFINISH(euc, yn2[rr], cn2, ad[rr], dv)
    sd  += dv[0]+dv[1]+dv[2]+dv[3];
    sd2 += dv[0]*dv[0]+dv[1]*dv[1]+dv[2]*dv[2]+dv[3]*dv[3];
    float4 o4; o4.x=dv[0]; o4.y=dv[1]; o4.z=dv[2]; o4.w=dv[3];
    *reinterpret_cast<float4*>(&Dt[rr][j4]) = o4;
  }
  sd = wsum(sd); sd2 = wsum(sd2);
  if (lane == 0){ s1s[w] = sd; s2s[w] = sd2; }
  __syncthreads();
  if (t == 0){
    double S  = (double)s1s[0] + (double)s1s[1] + (double)s1s[2] + (double)s1s[3];
    double S2 = (double)s2s[0] + (double)s2s[1] + (double)s2s[2] + (double)s2s[3];
    atomicAdd(&sums[m*2 + 0], S);
    atomicAdd(&sums[m*2 + 1], S2);
  }

  // ---- per-wave selection: wave w handles rows 4w..4w+3 ----
  for (int rr2 = 0; rr2 < 4; rr2++){
    int row = w*4 + rr2;
    float dreg[16];
    #pragma unroll
    for (int k2=0;k2<4;k2++){
      float4 v = ld4(&Dt[row][4*lane + 256*k2]);
      dreg[4*k2+0]=v.x; dreg[4*k2+1]=v.y; dreg[4*k2+2]=v.z; dreg[4*k2+3]=v.w;
    }
    float lmin = 3.4e38f, lmax = -3.4e38f;
    #pragma unroll
    for (int k=0;k<16;k++){ lmin = fminf(lmin,dreg[k]); lmax = fmaxf(lmax,dreg[k]); }
    float Dmin = wminr(lmin);
    float Dmax = wmaxr(lmax);
    float lz = 0.f;
    #pragma unroll
    for (int k=0;k<16;k++) lz += expf((Dmin - dreg[k])*0.1f);
    float Z = wsum(lz);
    float invZ = 1.0f/Z;
    float preg[16];
    #pragma unroll
    for (int k=0;k<16;k++) preg[k] = expf((Dmin - dreg[k])*0.1f)*invZ;
    float le = 0.f;
    #pragma unroll
    for (int k=0;k<16;k++) le += preg[k]*logf(preg[k] + 1e-8f);
    float ent = -wsum(le);
    float decay = expf(-ent);
    float range = Dmax - Dmin;
    float scale1 = 256.0f / fmaxf(range, 1e-30f);

    if (lane==0){ selI4[w]=255; selC4[w]=0.8f; cnt4[w]=0; }
    #pragma unroll
    for (int i=0;i<4;i++) hist[w][lane*4+i] = 0.f;
    __syncthreads();
    #pragma unroll
    for (int k=0;k<16;k++){
      int b1 = (int)((dreg[k]-Dmin)*scale1); b1 = (b1>255)?255:b1;
      atomicAdd(&hist[w][b1], preg[k]);
    }
    __syncthreads();
    {
      float h0=hist[w][lane*4+0], h1=hist[w][lane*4+1], h2=hist[w][lane*4+2], h3=hist[w][lane*4+3];
      float tot = h0+h1+h2+h3;
      float incl = tot;
      #pragma unroll
      for (int o=1;o<64;o<<=1){ float v = __shfl_up(incl,o); if (lane>=o) incl += v; }
      float excl = incl - tot;
      float c0=excl, c1=excl+h0, c2=c1+h1, c3=c2+h2;
      bool f0=(c0<=0.8f && 0.8f<c0+h0), f1=(c1<=0.8f && 0.8f<c1+h1),
           f2=(c2<=0.8f && 0.8f<c2+h2), f3=(c3<=0.8f && 0.8f<c3+h3);
      if (f0){ selI4[w]=lane*4+0; selC4[w]=c0; }
      if (f1){ selI4[w]=lane*4+1; selC4[w]=c1; }
      if (f2){ selI4[w]=lane*4+2; selC4[w]=c2; }
      if (f3){ selI4[w]=lane*4+3; selC4[w]=c3; }
      if (__ballot(f0||f1||f2||f3) == 0ull){   // crack fallback
        int bi = 10000; float bc = 0.f;
        if (c0>0.8f){bi=lane*4+0;bc=c0;} else if (c1>0.8f){bi=lane*4+1;bc=c1;}
        else if (c2>0.8f){bi=lane*4+2;bc=c2;} else if (c3>0.8f){bi=lane*4+3;bc=c3;}
        int mn = bi;
        #pragma unroll
        for (int o=32;o;o>>=1) mn = min(mn, __shfl_xor(mn,o));
        if (mn==bi && bi<10000){ selI4[w]=bi; selC4[w]=bc; }
      }
    }
    __syncthreads();
    int B1 = selI4[w]; float cb1 = selC4[w];
    float lo2 = Dmin + (float)B1/scale1;
    float scale2 = scale1*256.0f;
    if (lane==0){ selI4[w]=255; selC4[w]=cb1; }
    #pragma unroll
    for (int i=0;i<4;i++) hist[w][lane*4+i] = 0.f;
    __syncthreads();
    #pragma unroll
    for (int k=0;k<16;k++){
      int b1 = (int)((dreg[k]-Dmin)*scale1); b1 = (b1>255)?255:b1;
      if (b1 == B1){
        int b2 = (int)((dreg[k]-lo2)*scale2); b2 = (b2<0)?0:((b2>255)?255:b2);
        atomicAdd(&hist[w][b2], preg[k]);
      }
    }
    __syncthreads();
    {
      float h0=hist[w][lane*4+0], h1=hist[w][lane*4+1], h2=hist[w][lane*4+2], h3=hist[w][lane*4+3];
      float tot = h0+h1+h2+h3;
      float incl = tot;
      #pragma unroll
      for (int o=1;o<64;o<<=1){ float v = __shfl_up(incl,o); if (lane>=o) incl += v; }
      float excl = incl - tot;
      float c0=cb1+excl, c1=c0+h0, c2=c1+h1, c3=c2+h2;
      bool f0=(c0<=0.8f && 0.8f<c0+h0), f1=(c1<=0.8f && 0.8f<c1+h1),
           f2=(c2<=0.8f && 0.8f<c2+h2), f3=(c3<=0.8f && 0.8f<c3+h3);
      if (f0){ selI4[w]=lane*4+0; selC4[w]=c0; }
      if (f1){ selI4[w]=lane*4+1; selC4[w]=c1; }
      if (f2){ selI4[w]=lane*4+2; selC4[w]=c2; }
      if (f3){ selI4[w]=lane*4+3; selC4[w]=c3; }
      if (__ballot(f0||f1||f2||f3) == 0ull){
        int bi = 10000; float bc = 0.f;
        if (c0>0.8f){bi=lane*4+0;bc=c0;} else if (c1>0.8f){bi=lane*4+1;bc=c1;}
        else if (c2>0.8f){bi=lane*4+2;bc=c2;} else if (c3>0.8f){bi=lane*4+3;bc=c3;}
        int mn = bi;
        #pragma unroll
        for (int o=32;o;o>>=1) mn = min(mn, __shfl_xor(mn,o));
        if (mn==bi && bi<10000){ selI4[w]=bi; selC4[w]=bc; }
      }
    }
    __syncthreads();
    int B2 = selI4[w]; float cb2 = selC4[w];

    // candidates in (B1,B2)
    #pragma unroll
    for (int k=0;k<16;k++){
      int b1 = (int)((dreg[k]-Dmin)*scale1); b1 = (b1>255)?255:b1;
      if (b1 == B1){
        int b2 = (int)((dreg[k]-lo2)*scale2); b2 = (b2<0)?0:((b2>255)?255:b2);
        if (b2 == B2){
          int c = atomicAdd(&cnt4[w], 1);
          if (c < 64){
            int j = (k>>2)*256 + 4*lane + (k&3);
            candj[w][c] = j;
            candd[w][c] = dreg[k];
            candb[w][c] = monob(dreg[k]);
          }
        }
      }
    }
    __syncthreads();
    // lex-max element strictly before sub-bucket (B1,B2) — all selected
    ull em = 0;
    #pragma unroll
    for (int k=0;k<16;k++){
      int b1 = (int)((dreg[k]-Dmin)*scale1); b1 = (b1>255)?255:b1;
      bool qual;
      if (b1 < B1) qual = true;
      else if (b1 > B1) qual = false;
      else {
        int b2 = (int)((dreg[k]-lo2)*scale2); b2 = (b2<0)?0:((b2>255)?255:b2);
        qual = (b2 < B2);
      }
      if (qual){
        int j = (k>>2)*256 + 4*lane + (k&3);
        ull key = ((ull)monob(dreg[k]) << 32) | (u32)j;
        if (key > em) em = key;
      }
    }
    em = wmaxu64(em);
    if (lane == 0){
      int n = cnt4[w]; n = (n>64)?64:n;
      ull best = em;
      for (int a=0;a<n;a++){
        float da = candd[w][a]; int ja = candj[w][a];
        float acc = cb2;
        for (int bb=0;bb<n;bb++){
          float db = candd[w][bb]; int jb = candj[w][bb];
          if (db < da || (db == da && jb <= ja))
            acc += expf((Dmin - db)*0.1f)*invZ;
        }
        if (acc <= 0.8f){
          ull key = ((ull)candb[w][a] << 32) | (u32)ja;
          if (key > best) best = key;
        }
      }
      rec[(size_t)m*NN + i0 + row] = make_uint4((u32)(best>>32), (u32)(best & 0xFFFFFFFFu),
                                               __float_as_uint(Dmax), __float_as_uint(decay));
    }
    __syncthreads();
  }
}

// ---------------- kapp: fused D+S GEMM + mask + softmax + o-accum ----------------
__global__ __launch_bounds__(256, 3)
void kapp(const float* __restrict__ x1, const float* __restrict__ x2, const float* __restrict__ x3,
          const float* __restrict__ f, const float* __restrict__ p,
          const float* __restrict__ fnT, const float* __restrict__ pT,
          const float* __restrict__ nrm2g, const float* __restrict__ baseg,
          const uint4* __restrict__ rec, float* __restrict__ out){
  __shared__ __align__(16) float yl[8][64];
  __shared__ __align__(16) float pyl[8][64];
  __shared__ __align__(16) float Sm[8][NN];        // 32KB
  __shared__ __align__(16) float opart[4][8][64];  // 8KB
  __shared__ float yn2[8];
  __shared__ u32 dBb[8]; __shared__ u32 jBl[8];
  __shared__ float th[8];

  int bid = blockIdx.x;
  int tile = bid & 127;            // 128 tiles of 8 rows
  int q = (bid >> 7) % 9;
  int b = bid / 1152;
  int r = q / 3, s = q - 3*r;
  bool euc = (r == s);
  int m = b*9 + q;
  int i0 = tile*8;
  int t = threadIdx.x;
  int w = t >> 6, lane = t & 63;

  if (t < 8){
    yn2[t] = nrm2g[(size_t)(r*BB + b)*NN + i0 + t];
    uint4 R = rec[(size_t)m*NN + i0 + t];
    dBb[t] = R.x; jBl[t] = R.y;
    float Dmax = __uint_as_float(R.z);
    float decay = __uint_as_float(R.w);
    float Tb = baseg[m];
    th[t] = (Tb + 0.01f*decay) / (1.0f + 0.01f*decay/Dmax);
  }
  __syncthreads();
  for (int idx = t; idx < 512; idx += 256){
    int rr = idx >> 6, c = idx & 63;
    float v = f[((size_t)(r*BB + b)*NN + i0 + rr)*CC + c];
    if (!euc) v *= 1.0f / fmaxf(sqrtf(yn2[rr]), 1e-12f);
    yl[rr][c] = v;
    pyl[rr][c] = p[((size_t)(r*BB + b)*NN + i0 + rr)*CC + c];
  }
  __syncthreads();

  const float* xs = (s==0)?x1:((s==1)?x2:x3);
  const float* colD = euc ? (xs + (size_t)(b*CC)*NN) : (fnT + (size_t)((s*BB + b)*CC)*NN);
  const float* colP = pT + (size_t)((s*BB + b)*CC)*NN;
  int j4 = 4*t;

  float ad[8][4];
  #pragma unroll
  for (int rr=0;rr<8;rr++){ ad[rr][0]=0.f; ad[rr][1]=0.f; ad[rr][2]=0.f; ad[rr][3]=0.f; }
  GEMM_COLS(8, colD, yl, j4, ad)

  float ap[8][4];
  #pragma unroll
  for (int rr=0;rr<8;rr++){ ap[rr][0]=0.f; ap[rr][1]=0.f; ap[rr][2]=0.f; ap[rr][3]=0.f; }
  GEMM_COLS(8, colP, pyl, j4, ap)

  float4 cn2 = make_float4(0.f,0.f,0.f,0.f);
  if (euc) cn2 = ld4(nrm2g + (size_t)(s*BB + b)*NN + j4);

  #pragma unroll
  for (int rr=0;rr<8;rr++){
    float dv[4];
    DFINISH(euc, yn2[rr], cn2, ad[rr], dv)
    u32 db = dBb[rr]; u32 jb = jBl[rr]; float tt = th[rr];
    float4 sv;
    {
      u32 bits = monob(dv[0]); u32 j = (u32)(j4+0);
      bool sel = (bits < db) || (bits == db && j <= jb);
      sv.x = (sel && dv[0] < tt) ? ap[rr][0] : 0.f;
    }
    {
      u32 bits = monob(dv[1]); u32 j = (u32)(j4+1);
      bool sel = (bits < db) || (bits == db && j <= jb);
      sv.y = (sel && dv[1] < tt) ? ap[rr][1] : 0.f;
    }
    {
      u32 bits = monob(dv[2]); u32 j = (u32)(j4+2);
      bool sel = (bits < db) || (bits == db && j <= jb);
      sv.z = (sel && dv[2] < tt) ? ap[rr][2] : 0.f;
    }
    {
      u32 bits = monob(dv[3]); u32 j = (u32)(j4+3);
      bool sel = (bits < db) || (bits == db && j <= jb);
      sv.w = (sel && dv[3] < tt) ? ap[rr][3] : 0.f;
    }
    *reinterpret_cast<float4*>(&Sm[rr][j4]) = sv;
  }
  __syncthreads();

  // row softmax: wave w owns rows 2w, 2w+1
  #pragma unroll
  for (int e=0;e<2;e++){
    int row = 2*w + e;
    float s16[16];
    #pragma unroll
    for (int k2=0;k2<4;k2++){
      float4 v = ld4(&Sm[row][4*lane + 256*k2]);
      s16[4*k2+0]=v.x; s16[4*k2+1]=v.y; s16[4*k2+2]=v.z; s16[4*k2+3]=v.w;
    }
    float lm = -3.4e38f;
    #pragma unroll
    for (int k=0;k<16;k++) lm = fmaxf(lm, s16[k]);
    float M = wmaxr(lm);
    float ls = 0.f;
    #pragma unroll
    for (int k=0;k<16;k++) ls += expf(s16[k]-M);
    float Z2 = wsum(ls);
    float iZ2 = 1.0f/Z2;
    #pragma unroll
    for (int k2=0;k2<4;k2++){
      float4 v;
      v.x = expf(s16[4*k2+0]-M)*iZ2;
      v.y = expf(s16[4*k2+1]-M)*iZ2;
      v.z = expf(s16[4*k2+2]-M)*iZ2;
      v.w = expf(s16[4*k2+3]-M)*iZ2;
      *reinterpret_cast<float4*>(&Sm[row][4*lane + 256*k2]) = v;
    }
  }
  __syncthreads();

  // o-accum: thread (cg = t&15 channel-quad, jj = t>>4), j = jj + 16*mm
  int cg = t & 15, jj = t >> 4;
  float acc[8][4];
  #pragma unroll
  for (int rr=0;rr<8;rr++){ acc[rr][0]=0.f; acc[rr][1]=0.f; acc[rr][2]=0.f; acc[rr][3]=0.f; }
  const float* fs = f + (size_t)((s*BB + b)*NN)*CC;
  for (int mm=0; mm<64; mm++){
    int j = jj + 16*mm;
    float4 fv = ld4(&fs[(size_t)j*CC + 4*cg]);
    #pragma unroll
    for (int rr=0;rr<8;rr++){
      float pv = Sm[rr][j];
      acc[rr][0] = fmaf(pv, fv.x, acc[rr][0]);
      acc[rr][1] = fmaf(pv, fv.y, acc[rr][1]);
      acc[rr][2] = fmaf(pv, fv.z, acc[rr][2]);
      acc[rr][3] = fmaf(pv, fv.w, acc[rr][3]);
    }
  }
  #pragma unroll
  for (int rr=0;rr<8;rr++){
    #pragma unroll
    for (int i=0;i<4;i++){
      acc[rr][i] += __shfl_xor(acc[rr][i], 16);
      acc[rr][i] += __shfl_xor(acc[rr][i], 32);
    }
  }
  if (lane < 16){
    #pragma unroll
    for (int rr=0;rr<8;rr++){
      float4 v; v.x=acc[rr][0]; v.y=acc[rr][1]; v.z=acc[rr][2]; v.w=acc[rr][3];
      *reinterpret_cast<float4*>(&opart[w][rr][4*cg]) = v;
    }
  }
  __syncthreads();
  #pragma unroll
  for (int e=0;e<2;e++){
    int idx = t + 256*e;
    int rr = idx >> 6, c = idx & 63;
    float v = opart[0][rr][c]+opart[1][rr][c]+opart[2][rr][c]+opart[3][rr][c];
    atomicAdd(&out[(size_t)(b*CC + c)*NN + i0 + rr], v);
  }
}

extern "C" void kernel_launch(void* const* d_in, const int* in_sizes, int n_in,
                              void* d_out, int out_size, void* d_ws, size_t ws_size,
                              hipStream_t stream){
  const float* x1 = (const float*)d_in[0];
  const float* x2 = (const float*)d_in[1];
  const float* x3 = (const float*)d_in[2];
  const float* w1 = (const float*)d_in[3];
  const float* b1 = (const float*)d_in[4];
  const float* w2 = (const float*)d_in[5];
  const float* b2 = (const float*)d_in[6];
  const float* w3 = (const float*)d_in[7];
  const float* b3 = (const float*)d_in[8];

  char* ws = (char*)d_ws;
  const size_t SZ = (size_t)3*BB*NN*CC*sizeof(float);   // 1.5MB each
  float*  f    = (float*)(ws);
  float*  p    = (float*)(ws + SZ);
  float*  fnT  = (float*)(ws + 2*SZ);
  float*  pT   = (float*)(ws + 3*SZ);
  float*  nrm2 = (float*)(ws + 4*SZ);
  double* sums = (double*)(ws + 4*SZ + 32768);
  float*  baseg= (float*)(ws + 4*SZ + 32768 + 512);
  uint4*  rec  = (uint4*)(ws + 4*SZ + 65536);           // 18*1024*16B = 288KB

  float* out = (float*)d_out;

  kz  <<<512, 256, 0, stream>>>(out, sums);
  k0a <<<96,  256, 0, stream>>>(x1, x2, x3, f);
  k0b <<<384, 256, 0, stream>>>(f, w1, b1, w2, b2, w3, b3, p, pT, fnT, nrm2);
  ksel<<<1152,256, 0, stream>>>(x1, x2, x3, f, fnT, nrm2, sums, rec);
  k2  <<<1,   64,  0, stream>>>(sums, baseg);
  kapp<<<2304,256, 0, stream>>>(x1, x2, x3, f, p, fnT, pT, nrm2, baseg, rec, out);
}

// Round 7
// 440.363 us; speedup vs baseline: 13.9595x; 12.4386x over previous
//
#include <hip/hip_runtime.h>

#define NN 1024
#define CC 64
#define BB 2

typedef unsigned long long ull;
typedef unsigned int u32;

__device__ __forceinline__ float wsum(float v){
  #pragma unroll
  for (int o=32;o;o>>=1) v += __shfl_xor(v,o);
  return v;
}
__device__ __forceinline__ float wmaxr(float v){
  #pragma unroll
  for (int o=32;o;o>>=1) v = fmaxf(v, __shfl_xor(v,o));
  return v;
}
__device__ __forceinline__ float wminr(float v){
  #pragma unroll
  for (int o=32;o;o>>=1) v = fminf(v, __shfl_xor(v,o));
  return v;
}
__device__ __forceinline__ ull wmaxu64(ull v){
  #pragma unroll
  for (int o=32;o;o>>=1){ ull x = __shfl_xor(v,o); v = (x>v)?x:v; }
  return v;
}
__device__ __forceinline__ float4 ld4(const float* p){ return *reinterpret_cast<const float4*>(p); }
__device__ __forceinline__ u32 monob(float d){
  u32 u = __float_as_uint(d);
  return (u & 0x80000000u) ? ~u : (u | 0x80000000u);
}

// GEMM inner loop. "unroll 4" (NOT full unroll) is load-bearing: full unroll let
// the scheduler hoist all 64 column loads -> live range explosion -> accumulators
// spilled to scratch (R5/R6: 11-16GB HBM traffic, VALUBusy 2%, VGPR 84). R3's
// working k1a used unroll 4. Identical text in ksel & kapp keeps the fmaf chain
// bitwise-identical so the exact d==dB boundary test stays valid.
#define GEMM_COLS(R, col, ylm, j4v, adv)                                          \
  { _Pragma("unroll 4")                                                           \
    for (int cc=0; cc<16; cc++){                                                  \
      float4 c0 = ld4((col) + (size_t)(cc*4+0)*NN + (j4v));                       \
      float4 c1 = ld4((col) + (size_t)(cc*4+1)*NN + (j4v));                       \
      float4 c2 = ld4((col) + (size_t)(cc*4+2)*NN + (j4v));                       \
      float4 c3 = ld4((col) + (size_t)(cc*4+3)*NN + (j4v));                       \
      _Pragma("unroll")                                                           \
      for (int rr=0; rr<(R); rr++){                                               \
        float4 y4 = *reinterpret_cast<const float4*>(&(ylm)[rr][cc*4]);           \
        float a0 = adv[rr][0], a1 = adv[rr][1], a2 = adv[rr][2], a3 = adv[rr][3]; \
        a0 = fmaf(y4.x,c0.x,a0); a0 = fmaf(y4.y,c1.x,a0); a0 = fmaf(y4.z,c2.x,a0); a0 = fmaf(y4.w,c3.x,a0); \
        a1 = fmaf(y4.x,c0.y,a1); a1 = fmaf(y4.y,c1.y,a1); a1 = fmaf(y4.z,c2.y,a1); a1 = fmaf(y4.w,c3.y,a1); \
        a2 = fmaf(y4.x,c0.z,a2); a2 = fmaf(y4.y,c1.z,a2); a2 = fmaf(y4.z,c2.z,a2); a2 = fmaf(y4.w,c3.z,a2); \
        a3 = fmaf(y4.x,c0.w,a3); a3 = fmaf(y4.y,c1.w,a3); a3 = fmaf(y4.z,c2.w,a3); a3 = fmaf(y4.w,c3.w,a3); \
        adv[rr][0]=a0; adv[rr][1]=a1; adv[rr][2]=a2; adv[rr][3]=a3;               \
      }                                                                           \
    }                                                                             \
  }

// D epilogue macro — identical value chain in both kernels.
#define DFINISH(eucv, yn2r, cn2v, adr, dvv)                                       \
  { if (eucv){                                                                    \
      dvv[0] = sqrtf(fmaxf(fmaf(-2.0f, adr[0], (yn2r) + (cn2v).x), 1e-12f));      \
      dvv[1] = sqrtf(fmaxf(fmaf(-2.0f, adr[1], (yn2r) + (cn2v).y), 1e-12f));      \
      dvv[2] = sqrtf(fmaxf(fmaf(-2.0f, adr[2], (yn2r) + (cn2v).z), 1e-12f));      \
      dvv[3] = sqrtf(fmaxf(fmaf(-2.0f, adr[3], (yn2r) + (cn2v).w), 1e-12f));      \
    } else {                                                                      \
      dvv[0] = 1.0f - adr[0]; dvv[1] = 1.0f - adr[1];                             \
      dvv[2] = 1.0f - adr[2]; dvv[3] = 1.0f - adr[3];                             \
    }                                                                             \
  }

// ---------------- zero init ----------------
__global__ void kz(float* __restrict__ out, double* __restrict__ sums){
  int i = blockIdx.x*256 + threadIdx.x;
  if (i < BB*CC*NN) out[i] = 0.0f;
  if (i < 36) sums[i] = 0.0;
}

// ---------------- K0a: transpose x[b][c][n] -> f[s][b][n][c] ----------------
__global__ __launch_bounds__(256)
void k0a(const float* __restrict__ x1, const float* __restrict__ x2, const float* __restrict__ x3,
         float* __restrict__ f){
  int bid = blockIdx.x;
  int tile = bid & 15;
  int b = (bid >> 4) & 1;
  int s = bid >> 5;
  const float* x = (s==0)?x1:((s==1)?x2:x3);
  __shared__ float lds[64][65];
  int i0 = tile*64;
  for (int idx = threadIdx.x; idx < 4096; idx += 256){
    int c = idx >> 6, ii = idx & 63;
    lds[c][ii] = x[(size_t)(b*CC + c)*NN + i0 + ii];
  }
  __syncthreads();
  for (int idx = threadIdx.x; idx < 4096; idx += 256){
    int ii = idx >> 6, c = idx & 63;
    f[((size_t)(s*BB + b)*NN + i0 + ii)*CC + c] = lds[c][ii];
  }
}

// ---------------- K0b: norms, fnT, p, pT ----------------
__global__ __launch_bounds__(256)
void k0b(const float* __restrict__ f,
         const float* __restrict__ w1, const float* __restrict__ b1,
         const float* __restrict__ w2, const float* __restrict__ b2,
         const float* __restrict__ w3, const float* __restrict__ b3,
         float* __restrict__ p, float* __restrict__ pT,
         float* __restrict__ fnT, float* __restrict__ nrm2g){
  int bid = blockIdx.x;
  int chunk = bid & 63;
  int b = (bid >> 6) & 1;
  int s = bid >> 7;
  const float* w = (s==0)?w1:((s==1)?w2:w3);
  const float* bias = (s==0)?b1:((s==1)?b2:b3);
  __shared__ float wl[64][65];
  __shared__ float fr[16][65];
  __shared__ float n2[16];
  int i0 = chunk*16;
  int t = threadIdx.x;
  for (int idx = t; idx < 4096; idx += 256){
    int o = idx >> 6, c = idx & 63;
    wl[o][c] = w[idx];
  }
  for (int idx = t; idx < 1024; idx += 256){
    int rr = idx >> 6, c = idx & 63;
    fr[rr][c] = f[((size_t)(s*BB + b)*NN + i0 + rr)*CC + c];
  }
  __syncthreads();
  {
    int r = t >> 4, l = t & 15;
    float pv = 0.f;
    for (int c = l; c < 64; c += 16) pv += fr[r][c]*fr[r][c];
    #pragma unroll
    for (int o=8;o;o>>=1) pv += __shfl_down(pv, o, 16);
    if (l == 0) n2[r] = pv;
  }
  __syncthreads();
  if (t < 16) nrm2g[(size_t)(s*BB + b)*NN + i0 + t] = n2[t];
  for (int idx = t; idx < 1024; idx += 256){
    int rr = idx >> 6, c = idx & 63;
    float rinv = 1.0f / fmaxf(sqrtf(n2[rr]), 1e-12f);
    fnT[((size_t)(s*BB + b)*CC + c)*NN + i0 + rr] = fr[rr][c]*rinv;
  }
  for (int idx = t; idx < 1024; idx += 256){
    int rr = idx >> 6, o = idx & 63;
    float acc = bias[o];
    #pragma unroll
    for (int c = 0; c < 64; c++) acc += fr[rr][c]*wl[o][c];
    p [((size_t)(s*BB + b)*NN + i0 + rr)*CC + o] = acc;
    pT[((size_t)(s*BB + b)*CC + o)*NN + i0 + rr] = acc;
  }
}

// ---------------- K2: mu + alpha*sigma ----------------
__global__ void k2(const double* __restrict__ sums, float* __restrict__ baseg){
  int t = threadIdx.x;
  if (t < 18){
    double S = sums[t*2], S2 = sums[t*2+1];
    const double Nsq = 1048576.0;
    double mu = S / Nsq;
    double var = (S2 - S*S/Nsq) / (Nsq - 1.0);
    double sg = var > 0.0 ? sqrt(var) : 0.0;
    baseg[t] = (float)(mu + 0.08*sg);
  }
}

// ---------------- ksel: D-GEMM + stats + per-row selection boundary ----------------
// rec[m*NN+i] = {dB_bits, jB, Dmax_bits, decay_bits}; selected(j) <=> (bits<dB)||(bits==dB && j<=jB)
__global__ __launch_bounds__(256, 2)
void ksel(const float* __restrict__ x1, const float* __restrict__ x2, const float* __restrict__ x3,
          const float* __restrict__ f, const float* __restrict__ fnT,
          const float* __restrict__ nrm2g, double* __restrict__ sums, uint4* __restrict__ rec){
  __shared__ __align__(16) float yl[16][64];     // 4KB
  __shared__ __align__(16) float Dt[16][NN];     // 64KB
  __shared__ float hist[4][256];                 // 4KB
  __shared__ float candd[4][64];
  __shared__ int   candj[4][64];
  __shared__ u32   candb[4][64];
  __shared__ float yn2[16];
  __shared__ int   cnt4[4];
  __shared__ int   selI4[4];
  __shared__ float selC4[4];
  __shared__ float s1s[4], s2s[4];

  int bid = blockIdx.x;
  int tile = bid & 63;             // 64 tiles of 16 rows
  int q = (bid >> 6) % 9;
  int b = bid / 576;
  int r = q / 3, s = q - 3*r;
  bool euc = (r == s);
  int m = b*9 + q;
  int i0 = tile*16;
  int t = threadIdx.x;
  int w = t >> 6, lane = t & 63;

  if (t < 16) yn2[t] = nrm2g[(size_t)(r*BB + b)*NN + i0 + t];
  __syncthreads();
  for (int idx = t; idx < 1024; idx += 256){
    int rr = idx >> 6, c = idx & 63;
    float v = f[((size_t)(r*BB + b)*NN + i0 + rr)*CC + c];
    if (!euc) v *= 1.0f / fmaxf(sqrtf(yn2[rr]), 1e-12f);
    yl[rr][c] = v;
  }
  __syncthreads();

  const float* xs = (s==0)?x1:((s==1)?x2:x3);
  const float* colD = euc ? (xs + (size_t)(b*CC)*NN) : (fnT + (size_t)((s*BB + b)*CC)*NN);
  int j4 = 4*t;

  float ad[16][4];
  #pragma unroll
  for (int rr=0;rr<16;rr++){ ad[rr][0]=0.f; ad[rr][1]=0.f; ad[rr][2]=0.f; ad[rr][3]=0.f; }
  GEMM_COLS(16, colD, yl, j4, ad)

  float4 cn2 = make_float4(0.f,0.f,0.f,0.f);
  if (euc) cn2 = ld4(nrm2g + (size_t)(s*BB + b)*NN + j4);

  float sd = 0.f, sd2 = 0.f;
  #pragma unroll
  for (int rr=0;rr<16;rr++){
    float dv[4];
    DFINISH(euc, yn2[rr], cn2, ad[rr], dv)
    sd  += dv[0]+dv[1]+dv[2]+dv[3];
    sd2 += dv[0]*dv[0]+dv[1]*dv[1]+dv[2]*dv[2]+dv[3]*dv[3];
    float4 o4; o4.x=dv[0]; o4.y=dv[1]; o4.z=dv[2]; o4.w=dv[3];
    *reinterpret_cast<float4*>(&Dt[rr][j4]) = o4;
  }
  sd = wsum(sd); sd2 = wsum(sd2);
  if (lane == 0){ s1s[w] = sd; s2s[w] = sd2; }
  __syncthreads();
  if (t == 0){
    double S  = (double)s1s[0] + (double)s1s[1] + (double)s1s[2] + (double)s1s[3];
    double S2 = (double)s2s[0] + (double)s2s[1] + (double)s2s[2] + (double)s2s[3];
    atomicAdd(&sums[m*2 + 0], S);
    atomicAdd(&sums[m*2 + 1], S2);
  }

  // ---- per-wave selection: wave w handles rows 4w..4w+3 ----
  for (int rr2 = 0; rr2 < 4; rr2++){
    int row = w*4 + rr2;
    float dreg[16];
    #pragma unroll
    for (int k2=0;k2<4;k2++){
      float4 v = ld4(&Dt[row][4*lane + 256*k2]);
      dreg[4*k2+0]=v.x; dreg[4*k2+1]=v.y; dreg[4*k2+2]=v.z; dreg[4*k2+3]=v.w;
    }
    float lmin = 3.4e38f, lmax = -3.4e38f;
    #pragma unroll
    for (int k=0;k<16;k++){ lmin = fminf(lmin,dreg[k]); lmax = fmaxf(lmax,dreg[k]); }
    float Dmin = wminr(lmin);
    float Dmax = wmaxr(lmax);
    float lz = 0.f;
    #pragma unroll
    for (int k=0;k<16;k++) lz += expf((Dmin - dreg[k])*0.1f);
    float Z = wsum(lz);
    float invZ = 1.0f/Z;
    float preg[16];
    #pragma unroll
    for (int k=0;k<16;k++) preg[k] = expf((Dmin - dreg[k])*0.1f)*invZ;
    float le = 0.f;
    #pragma unroll
    for (int k=0;k<16;k++) le += preg[k]*logf(preg[k] + 1e-8f);
    float ent = -wsum(le);
    float decay = expf(-ent);
    float range = Dmax - Dmin;
    float scale1 = 256.0f / fmaxf(range, 1e-30f);

    if (lane==0){ selI4[w]=255; selC4[w]=0.8f; cnt4[w]=0; }
    #pragma unroll
    for (int i=0;i<4;i++) hist[w][lane*4+i] = 0.f;
    __syncthreads();
    #pragma unroll
    for (int k=0;k<16;k++){
      int b1 = (int)((dreg[k]-Dmin)*scale1); b1 = (b1>255)?255:b1;
      atomicAdd(&hist[w][b1], preg[k]);
    }
    __syncthreads();
    {
      float h0=hist[w][lane*4+0], h1=hist[w][lane*4+1], h2=hist[w][lane*4+2], h3=hist[w][lane*4+3];
      float tot = h0+h1+h2+h3;
      float incl = tot;
      #pragma unroll
      for (int o=1;o<64;o<<=1){ float v = __shfl_up(incl,o); if (lane>=o) incl += v; }
      float excl = incl - tot;
      float c0=excl, c1=excl+h0, c2=c1+h1, c3=c2+h2;
      bool f0=(c0<=0.8f && 0.8f<c0+h0), f1=(c1<=0.8f && 0.8f<c1+h1),
           f2=(c2<=0.8f && 0.8f<c2+h2), f3=(c3<=0.8f && 0.8f<c3+h3);
      if (f0){ selI4[w]=lane*4+0; selC4[w]=c0; }
      if (f1){ selI4[w]=lane*4+1; selC4[w]=c1; }
      if (f2){ selI4[w]=lane*4+2; selC4[w]=c2; }
      if (f3){ selI4[w]=lane*4+3; selC4[w]=c3; }
      if (__ballot(f0||f1||f2||f3) == 0ull){   // crack fallback
        int bi = 10000; float bc = 0.f;
        if (c0>0.8f){bi=lane*4+0;bc=c0;} else if (c1>0.8f){bi=lane*4+1;bc=c1;}
        else if (c2>0.8f){bi=lane*4+2;bc=c2;} else if (c3>0.8f){bi=lane*4+3;bc=c3;}
        int mn = bi;
        #pragma unroll
        for (int o=32;o;o>>=1) mn = min(mn, __shfl_xor(mn,o));
        if (mn==bi && bi<10000){ selI4[w]=bi; selC4[w]=bc; }
      }
    }
    __syncthreads();
    int B1 = selI4[w]; float cb1 = selC4[w];
    float lo2 = Dmin + (float)B1/scale1;
    float scale2 = scale1*256.0f;
    if (lane==0){ selI4[w]=255; selC4[w]=cb1; }
    #pragma unroll
    for (int i=0;i<4;i++) hist[w][lane*4+i] = 0.f;
    __syncthreads();
    #pragma unroll
    for (int k=0;k<16;k++){
      int b1 = (int)((dreg[k]-Dmin)*scale1); b1 = (b1>255)?255:b1;
      if (b1 == B1){
        int b2 = (int)((dreg[k]-lo2)*scale2); b2 = (b2<0)?0:((b2>255)?255:b2);
        atomicAdd(&hist[w][b2], preg[k]);
      }
    }
    __syncthreads();
    {
      float h0=hist[w][lane*4+0], h1=hist[w][lane*4+1], h2=hist[w][lane*4+2], h3=hist[w][lane*4+3];
      float tot = h0+h1+h2+h3;
      float incl = tot;
      #pragma unroll
      for (int o=1;o<64;o<<=1){ float v = __shfl_up(incl,o); if (lane>=o) incl += v; }
      float excl = incl - tot;
      float c0=cb1+excl, c1=c0+h0, c2=c1+h1, c3=c2+h2;
      bool f0=(c0<=0.8f && 0.8f<c0+h0), f1=(c1<=0.8f && 0.8f<c1+h1),
           f2=(c2<=0.8f && 0.8f<c2+h2), f3=(c3<=0.8f && 0.8f<c3+h3);
      if (f0){ selI4[w]=lane*4+0; selC4[w]=c0; }
      if (f1){ selI4[w]=lane*4+1; selC4[w]=c1; }
      if (f2){ selI4[w]=lane*4+2; selC4[w]=c2; }
      if (f3){ selI4[w]=lane*4+3; selC4[w]=c3; }
      if (__ballot(f0||f1||f2||f3) == 0ull){
        int bi = 10000; float bc = 0.f;
        if (c0>0.8f){bi=lane*4+0;bc=c0;} else if (c1>0.8f){bi=lane*4+1;bc=c1;}
        else if (c2>0.8f){bi=lane*4+2;bc=c2;} else if (c3>0.8f){bi=lane*4+3;bc=c3;}
        int mn = bi;
        #pragma unroll
        for (int o=32;o;o>>=1) mn = min(mn, __shfl_xor(mn,o));
        if (mn==bi && bi<10000){ selI4[w]=bi; selC4[w]=bc; }
      }
    }
    __syncthreads();
    int B2 = selI4[w]; float cb2 = selC4[w];

    // candidates in (B1,B2)
    #pragma unroll
    for (int k=0;k<16;k++){
      int b1 = (int)((dreg[k]-Dmin)*scale1); b1 = (b1>255)?255:b1;
      if (b1 == B1){
        int b2 = (int)((dreg[k]-lo2)*scale2); b2 = (b2<0)?0:((b2>255)?255:b2);
        if (b2 == B2){
          int c = atomicAdd(&cnt4[w], 1);
          if (c < 64){
            int j = (k>>2)*256 + 4*lane + (k&3);
            candj[w][c] = j;
            candd[w][c] = dreg[k];
            candb[w][c] = monob(dreg[k]);
          }
        }
      }
    }
    __syncthreads();
    // lex-max element strictly before sub-bucket (B1,B2) — all selected
    ull em = 0;
    #pragma unroll
    for (int k=0;k<16;k++){
      int b1 = (int)((dreg[k]-Dmin)*scale1); b1 = (b1>255)?255:b1;
      bool qual;
      if (b1 < B1) qual = true;
      else if (b1 > B1) qual = false;
      else {
        int b2 = (int)((dreg[k]-lo2)*scale2); b2 = (b2<0)?0:((b2>255)?255:b2);
        qual = (b2 < B2);
      }
      if (qual){
        int j = (k>>2)*256 + 4*lane + (k&3);
        ull key = ((ull)monob(dreg[k]) << 32) | (u32)j;
        if (key > em) em = key;
      }
    }
    em = wmaxu64(em);
    if (lane == 0){
      int n = cnt4[w]; n = (n>64)?64:n;
      ull best = em;
      for (int a=0;a<n;a++){
        float da = candd[w][a]; int ja = candj[w][a];
        float acc = cb2;
        for (int bb=0;bb<n;bb++){
          float db = candd[w][bb]; int jb = candj[w][bb];
          if (db < da || (db == da && jb <= ja))
            acc += expf((Dmin - db)*0.1f)*invZ;
        }
        if (acc <= 0.8f){
          ull key = ((ull)candb[w][a] << 32) | (u32)ja;
          if (key > best) best = key;
        }
      }
      rec[(size_t)m*NN + i0 + row] = make_uint4((u32)(best>>32), (u32)(best & 0xFFFFFFFFu),
                                               __float_as_uint(Dmax), __float_as_uint(decay));
    }
    __syncthreads();
  }
}

// ---------------- kapp: fused D+S GEMM + mask + softmax + o-accum ----------------
__global__ __launch_bounds__(256, 3)
void kapp(const float* __restrict__ x1, const float* __restrict__ x2, const float* __restrict__ x3,
          const float* __restrict__ f, const float* __restrict__ p,
          const float* __restrict__ fnT, const float* __restrict__ pT,
          const float* __restrict__ nrm2g, const float* __restrict__ baseg,
          const uint4* __restrict__ rec, float* __restrict__ out){
  __shared__ __align__(16) float yl[8][64];
  __shared__ __align__(16) float pyl[8][64];
  __shared__ __align__(16) float Sm[8][NN];        // 32KB
  __shared__ __align__(16) float opart[4][8][64];  // 8KB
  __shared__ float yn2[8];
  __shared__ u32 dBb[8]; __shared__ u32 jBl[8];
  __shared__ float th[8];

  int bid = blockIdx.x;
  int tile = bid & 127;            // 128 tiles of 8 rows
  int q = (bid >> 7) % 9;
  int b = bid / 1152;
  int r = q / 3, s = q - 3*r;
  bool euc = (r == s);
  int m = b*9 + q;
  int i0 = tile*8;
  int t = threadIdx.x;
  int w = t >> 6, lane = t & 63;

  if (t < 8){
    yn2[t] = nrm2g[(size_t)(r*BB + b)*NN + i0 + t];
    uint4 R = rec[(size_t)m*NN + i0 + t];
    dBb[t] = R.x; jBl[t] = R.y;
    float Dmax = __uint_as_float(R.z);
    float decay = __uint_as_float(R.w);
    float Tb = baseg[m];
    th[t] = (Tb + 0.01f*decay) / (1.0f + 0.01f*decay/Dmax);
  }
  __syncthreads();
  for (int idx = t; idx < 512; idx += 256){
    int rr = idx >> 6, c = idx & 63;
    float v = f[((size_t)(r*BB + b)*NN + i0 + rr)*CC + c];
    if (!euc) v *= 1.0f / fmaxf(sqrtf(yn2[rr]), 1e-12f);
    yl[rr][c] = v;
    pyl[rr][c] = p[((size_t)(r*BB + b)*NN + i0 + rr)*CC + c];
  }
  __syncthreads();

  const float* xs = (s==0)?x1:((s==1)?x2:x3);
  const float* colD = euc ? (xs + (size_t)(b*CC)*NN) : (fnT + (size_t)((s*BB + b)*CC)*NN);
  const float* colP = pT + (size_t)((s*BB + b)*CC)*NN;
  int j4 = 4*t;

  float ad[8][4];
  #pragma unroll
  for (int rr=0;rr<8;rr++){ ad[rr][0]=0.f; ad[rr][1]=0.f; ad[rr][2]=0.f; ad[rr][3]=0.f; }
  GEMM_COLS(8, colD, yl, j4, ad)

  float ap[8][4];
  #pragma unroll
  for (int rr=0;rr<8;rr++){ ap[rr][0]=0.f; ap[rr][1]=0.f; ap[rr][2]=0.f; ap[rr][3]=0.f; }
  GEMM_COLS(8, colP, pyl, j4, ap)

  float4 cn2 = make_float4(0.f,0.f,0.f,0.f);
  if (euc) cn2 = ld4(nrm2g + (size_t)(s*BB + b)*NN + j4);

  #pragma unroll
  for (int rr=0;rr<8;rr++){
    float dv[4];
    DFINISH(euc, yn2[rr], cn2, ad[rr], dv)
    u32 db = dBb[rr]; u32 jb = jBl[rr]; float tt = th[rr];
    float4 sv;
    {
      u32 bits = monob(dv[0]); u32 j = (u32)(j4+0);
      bool sel = (bits < db) || (bits == db && j <= jb);
      sv.x = (sel && dv[0] < tt) ? ap[rr][0] : 0.f;
    }
    {
      u32 bits = monob(dv[1]); u32 j = (u32)(j4+1);
      bool sel = (bits < db) || (bits == db && j <= jb);
      sv.y = (sel && dv[1] < tt) ? ap[rr][1] : 0.f;
    }
    {
      u32 bits = monob(dv[2]); u32 j = (u32)(j4+2);
      bool sel = (bits < db) || (bits == db && j <= jb);
      sv.z = (sel && dv[2] < tt) ? ap[rr][2] : 0.f;
    }
    {
      u32 bits = monob(dv[3]); u32 j = (u32)(j4+3);
      bool sel = (bits < db) || (bits == db && j <= jb);
      sv.w = (sel && dv[3] < tt) ? ap[rr][3] : 0.f;
    }
    *reinterpret_cast<float4*>(&Sm[rr][j4]) = sv;
  }
  __syncthreads();

  // row softmax: wave w owns rows 2w, 2w+1
  #pragma unroll
  for (int e=0;e<2;e++){
    int row = 2*w + e;
    float s16[16];
    #pragma unroll
    for (int k2=0;k2<4;k2++){
      float4 v = ld4(&Sm[row][4*lane + 256*k2]);
      s16[4*k2+0]=v.x; s16[4*k2+1]=v.y; s16[4*k2+2]=v.z; s16[4*k2+3]=v.w;
    }
    float lm = -3.4e38f;
    #pragma unroll
    for (int k=0;k<16;k++) lm = fmaxf(lm, s16[k]);
    float M = wmaxr(lm);
    float ls = 0.f;
    #pragma unroll
    for (int k=0;k<16;k++) ls += expf(s16[k]-M);
    float Z2 = wsum(ls);
    float iZ2 = 1.0f/Z2;
    #pragma unroll
    for (int k2=0;k2<4;k2++){
      float4 v;
      v.x = expf(s16[4*k2+0]-M)*iZ2;
      v.y = expf(s16[4*k2+1]-M)*iZ2;
      v.z = expf(s16[4*k2+2]-M)*iZ2;
      v.w = expf(s16[4*k2+3]-M)*iZ2;
      *reinterpret_cast<float4*>(&Sm[row][4*lane + 256*k2]) = v;
    }
  }
  __syncthreads();

  // o-accum: thread (cg = t&15 channel-quad, jj = t>>4), j = jj + 16*mm
  int cg = t & 15, jj = t >> 4;
  float acc[8][4];
  #pragma unroll
  for (int rr=0;rr<8;rr++){ acc[rr][0]=0.f; acc[rr][1]=0.f; acc[rr][2]=0.f; acc[rr][3]=0.f; }
  const float* fs = f + (size_t)((s*BB + b)*NN)*CC;
  for (int mm=0; mm<64; mm++){
    int j = jj + 16*mm;
    float4 fv = ld4(&fs[(size_t)j*CC + 4*cg]);
    #pragma unroll
    for (int rr=0;rr<8;rr++){
      float pv = Sm[rr][j];
      acc[rr][0] = fmaf(pv, fv.x, acc[rr][0]);
      acc[rr][1] = fmaf(pv, fv.y, acc[rr][1]);
      acc[rr][2] = fmaf(pv, fv.z, acc[rr][2]);
      acc[rr][3] = fmaf(pv, fv.w, acc[rr][3]);
    }
  }
  #pragma unroll
  for (int rr=0;rr<8;rr++){
    #pragma unroll
    for (int i=0;i<4;i++){
      acc[rr][i] += __shfl_xor(acc[rr][i], 16);
      acc[rr][i] += __shfl_xor(acc[rr][i], 32);
    }
  }
  if (lane < 16){
    #pragma unroll
    for (int rr=0;rr<8;rr++){
      float4 v; v.x=acc[rr][0]; v.y=acc[rr][1]; v.z=acc[rr][2]; v.w=acc[rr][3];
      *reinterpret_cast<float4*>(&opart[w][rr][4*cg]) = v;
    }
  }
  __syncthreads();
  #pragma unroll
  for (int e=0;e<2;e++){
    int idx = t + 256*e;
    int rr = idx >> 6, c = idx & 63;
    float v = opart[0][rr][c]+opart[1][rr][c]+opart[2][rr][c]+opart[3][rr][c];
    atomicAdd(&out[(size_t)(b*CC + c)*NN + i0 + rr], v);
  }
}

extern "C" void kernel_launch(void* const* d_in, const int* in_sizes, int n_in,
                              void* d_out, int out_size, void* d_ws, size_t ws_size,
                              hipStream_t stream){
  const float* x1 = (const float*)d_in[0];
  const float* x2 = (const float*)d_in[1];
  const float* x3 = (const float*)d_in[2];
  const float* w1 = (const float*)d_in[3];
  const float* b1 = (const float*)d_in[4];
  const float* w2 = (const float*)d_in[5];
  const float* b2 = (const float*)d_in[6];
  const float* w3 = (const float*)d_in[7];
  const float* b3 = (const float*)d_in[8];

  char* ws = (char*)d_ws;
  const size_t SZ = (size_t)3*BB*NN*CC*sizeof(float);   // 1.5MB each
  float*  f    = (float*)(ws);
  float*  p    = (float*)(ws + SZ);
  float*  fnT  = (float*)(ws + 2*SZ);
  float*  pT   = (float*)(ws + 3*SZ);
  float*  nrm2 = (float*)(ws + 4*SZ);
  double* sums = (double*)(ws + 4*SZ + 32768);
  float*  baseg= (float*)(ws + 4*SZ + 32768 + 512);
  uint4*  rec  = (uint4*)(ws + 4*SZ + 65536);           // 18*1024*16B = 288KB

  float* out = (float*)d_out;

  kz  <<<512, 256, 0, stream>>>(out, sums);
  k0a <<<96,  256, 0, stream>>>(x1, x2, x3, f);
  k0b <<<384, 256, 0, stream>>>(f, w1, b1, w2, b2, w3, b3, p, pT, fnT, nrm2);
  ksel<<<1152,256, 0, stream>>>(x1, x2, x3, f, fnT, nrm2, sums, rec);
  k2  <<<1,   64,  0, stream>>>(sums, baseg);
  kapp<<<2304,256, 0, stream>>>(x1, x2, x3, f, p, fnT, pT, nrm2, baseg, rec, out);
}

// Round 8
// 389.479 us; speedup vs baseline: 15.7833x; 1.1306x over previous
//
#include <hip/hip_runtime.h>

#define NN 1024
#define CC 64
#define BB 2

typedef unsigned long long ull;
typedef unsigned int u32;

#define WVB() __builtin_amdgcn_wave_barrier()

__device__ __forceinline__ float wsum(float v){
  #pragma unroll
  for (int o=32;o;o>>=1) v += __shfl_xor(v,o);
  return v;
}
__device__ __forceinline__ float wmaxr(float v){
  #pragma unroll
  for (int o=32;o;o>>=1) v = fmaxf(v, __shfl_xor(v,o));
  return v;
}
__device__ __forceinline__ float wminr(float v){
  #pragma unroll
  for (int o=32;o;o>>=1) v = fminf(v, __shfl_xor(v,o));
  return v;
}
__device__ __forceinline__ ull wmaxu64(ull v){
  #pragma unroll
  for (int o=32;o;o>>=1){ ull x = __shfl_xor(v,o); v = (x>v)?x:v; }
  return v;
}
__device__ __forceinline__ float4 ld4(const float* p){ return *reinterpret_cast<const float4*>(p); }
__device__ __forceinline__ u32 monob(float d){
  u32 u = __float_as_uint(d);
  return (u & 0x80000000u) ? ~u : (u | 0x80000000u);
}

// GEMM inner loop. "unroll 4" (NOT full unroll) is load-bearing: full unroll let
// the scheduler hoist all 64 column loads -> live range explosion -> accumulators
// spilled to scratch (R5/R6: 11-16GB HBM traffic, VALUBusy 2%, VGPR 84). R3/R7
// used unroll 4 and stayed in registers. Identical text in ksel & kapp keeps the
// per-row fmaf chain bitwise-identical so the exact d==dB boundary test is valid
// (R only adds/removes rows; each row's chain is unchanged).
#define GEMM_COLS(R, col, ylm, j4v, adv)                                          \
  { _Pragma("unroll 4")                                                           \
    for (int cc=0; cc<16; cc++){                                                  \
      float4 c0 = ld4((col) + (size_t)(cc*4+0)*NN + (j4v));                       \
      float4 c1 = ld4((col) + (size_t)(cc*4+1)*NN + (j4v));                       \
      float4 c2 = ld4((col) + (size_t)(cc*4+2)*NN + (j4v));                       \
      float4 c3 = ld4((col) + (size_t)(cc*4+3)*NN + (j4v));                       \
      _Pragma("unroll")                                                           \
      for (int rr=0; rr<(R); rr++){                                               \
        float4 y4 = *reinterpret_cast<const float4*>(&(ylm)[rr][cc*4]);           \
        float a0 = adv[rr][0], a1 = adv[rr][1], a2 = adv[rr][2], a3 = adv[rr][3]; \
        a0 = fmaf(y4.x,c0.x,a0); a0 = fmaf(y4.y,c1.x,a0); a0 = fmaf(y4.z,c2.x,a0); a0 = fmaf(y4.w,c3.x,a0); \
        a1 = fmaf(y4.x,c0.y,a1); a1 = fmaf(y4.y,c1.y,a1); a1 = fmaf(y4.z,c2.y,a1); a1 = fmaf(y4.w,c3.y,a1); \
        a2 = fmaf(y4.x,c0.z,a2); a2 = fmaf(y4.y,c1.z,a2); a2 = fmaf(y4.z,c2.z,a2); a2 = fmaf(y4.w,c3.z,a2); \
        a3 = fmaf(y4.x,c0.w,a3); a3 = fmaf(y4.y,c1.w,a3); a3 = fmaf(y4.z,c2.w,a3); a3 = fmaf(y4.w,c3.w,a3); \
        adv[rr][0]=a0; adv[rr][1]=a1; adv[rr][2]=a2; adv[rr][3]=a3;               \
      }                                                                           \
    }                                                                             \
  }

// D epilogue macro — identical value chain in both kernels.
#define DFINISH(eucv, yn2r, cn2v, adr, dvv)                                       \
  { if (eucv){                                                                    \
      dvv[0] = sqrtf(fmaxf(fmaf(-2.0f, adr[0], (yn2r) + (cn2v).x), 1e-12f));      \
      dvv[1] = sqrtf(fmaxf(fmaf(-2.0f, adr[1], (yn2r) + (cn2v).y), 1e-12f));      \
      dvv[2] = sqrtf(fmaxf(fmaf(-2.0f, adr[2], (yn2r) + (cn2v).z), 1e-12f));      \
      dvv[3] = sqrtf(fmaxf(fmaf(-2.0f, adr[3], (yn2r) + (cn2v).w), 1e-12f));      \
    } else {                                                                      \
      dvv[0] = 1.0f - adr[0]; dvv[1] = 1.0f - adr[1];                             \
      dvv[2] = 1.0f - adr[2]; dvv[3] = 1.0f - adr[3];                             \
    }                                                                             \
  }

// ---------------- zero init ----------------
__global__ void kz(float* __restrict__ out, double* __restrict__ sums){
  int i = blockIdx.x*256 + threadIdx.x;
  if (i < BB*CC*NN) out[i] = 0.0f;
  if (i < 36) sums[i] = 0.0;
}

// ---------------- K0a: transpose x[b][c][n] -> f[s][b][n][c] ----------------
__global__ __launch_bounds__(256)
void k0a(const float* __restrict__ x1, const float* __restrict__ x2, const float* __restrict__ x3,
         float* __restrict__ f){
  int bid = blockIdx.x;
  int tile = bid & 15;
  int b = (bid >> 4) & 1;
  int s = bid >> 5;
  const float* x = (s==0)?x1:((s==1)?x2:x3);
  __shared__ float lds[64][65];
  int i0 = tile*64;
  for (int idx = threadIdx.x; idx < 4096; idx += 256){
    int c = idx >> 6, ii = idx & 63;
    lds[c][ii] = x[(size_t)(b*CC + c)*NN + i0 + ii];
  }
  __syncthreads();
  for (int idx = threadIdx.x; idx < 4096; idx += 256){
    int ii = idx >> 6, c = idx & 63;
    f[((size_t)(s*BB + b)*NN + i0 + ii)*CC + c] = lds[c][ii];
  }
}

// ---------------- K0b: norms, fnT, p, pT ----------------
__global__ __launch_bounds__(256)
void k0b(const float* __restrict__ f,
         const float* __restrict__ w1, const float* __restrict__ b1,
         const float* __restrict__ w2, const float* __restrict__ b2,
         const float* __restrict__ w3, const float* __restrict__ b3,
         float* __restrict__ p, float* __restrict__ pT,
         float* __restrict__ fnT, float* __restrict__ nrm2g){
  int bid = blockIdx.x;
  int chunk = bid & 63;
  int b = (bid >> 6) & 1;
  int s = bid >> 7;
  const float* w = (s==0)?w1:((s==1)?w2:w3);
  const float* bias = (s==0)?b1:((s==1)?b2:b3);
  __shared__ float wl[64][65];
  __shared__ float fr[16][65];
  __shared__ float n2[16];
  int i0 = chunk*16;
  int t = threadIdx.x;
  for (int idx = t; idx < 4096; idx += 256){
    int o = idx >> 6, c = idx & 63;
    wl[o][c] = w[idx];
  }
  for (int idx = t; idx < 1024; idx += 256){
    int rr = idx >> 6, c = idx & 63;
    fr[rr][c] = f[((size_t)(s*BB + b)*NN + i0 + rr)*CC + c];
  }
  __syncthreads();
  {
    int r = t >> 4, l = t & 15;
    float pv = 0.f;
    for (int c = l; c < 64; c += 16) pv += fr[r][c]*fr[r][c];
    #pragma unroll
    for (int o=8;o;o>>=1) pv += __shfl_down(pv, o, 16);
    if (l == 0) n2[r] = pv;
  }
  __syncthreads();
  if (t < 16) nrm2g[(size_t)(s*BB + b)*NN + i0 + t] = n2[t];
  for (int idx = t; idx < 1024; idx += 256){
    int rr = idx >> 6, c = idx & 63;
    float rinv = 1.0f / fmaxf(sqrtf(n2[rr]), 1e-12f);
    fnT[((size_t)(s*BB + b)*CC + c)*NN + i0 + rr] = fr[rr][c]*rinv;
  }
  for (int idx = t; idx < 1024; idx += 256){
    int rr = idx >> 6, o = idx & 63;
    float acc = bias[o];
    #pragma unroll
    for (int c = 0; c < 64; c++) acc += fr[rr][c]*wl[o][c];
    p [((size_t)(s*BB + b)*NN + i0 + rr)*CC + o] = acc;
    pT[((size_t)(s*BB + b)*CC + o)*NN + i0 + rr] = acc;
  }
}

// ---------------- K2: mu + alpha*sigma ----------------
__global__ void k2(const double* __restrict__ sums, float* __restrict__ baseg){
  int t = threadIdx.x;
  if (t < 18){
    double S = sums[t*2], S2 = sums[t*2+1];
    const double Nsq = 1048576.0;
    double mu = S / Nsq;
    double var = (S2 - S*S/Nsq) / (Nsq - 1.0);
    double sg = var > 0.0 ? sqrt(var) : 0.0;
    baseg[t] = (float)(mu + 0.08*sg);
  }
}

// ---------------- ksel: D-GEMM + stats + per-row selection boundary ----------------
// 8-row tiles (LDS 43KB -> 3 blocks/CU vs R7's 16-row 75KB -> 2) and NO
// __syncthreads inside the selection loop: hist/cand/sel/cnt are wave-private,
// wave64 lockstep + compiler lgkmcnt ordering make wave-synchronous LDS safe.
// rec[m*NN+i] = {dB_bits, jB, Dmax_bits, decay_bits}; selected(j) <=> (bits<dB)||(bits==dB && j<=jB)
__global__ __launch_bounds__(256, 3)
void ksel(const float* __restrict__ x1, const float* __restrict__ x2, const float* __restrict__ x3,
          const float* __restrict__ f, const float* __restrict__ fnT,
          const float* __restrict__ nrm2g, double* __restrict__ sums, uint4* __restrict__ rec){
  __shared__ __align__(16) float yl[8][64];      // 2KB
  __shared__ __align__(16) float Dt[8][NN];      // 32KB
  __shared__ float hist[4][256];                 // 4KB
  __shared__ float candd[4][64];
  __shared__ int   candj[4][64];
  __shared__ u32   candb[4][64];
  __shared__ float yn2[8];
  __shared__ int   cnt4[4];
  __shared__ int   selI4[4];
  __shared__ float selC4[4];
  __shared__ float s1s[4], s2s[4];

  int bid = blockIdx.x;
  int tile = bid & 127;            // 128 tiles of 8 rows
  int q = (bid >> 7) % 9;
  int b = bid / 1152;
  int r = q / 3, s = q - 3*r;
  bool euc = (r == s);
  int m = b*9 + q;
  int i0 = tile*8;
  int t = threadIdx.x;
  int w = t >> 6, lane = t & 63;

  if (t < 8) yn2[t] = nrm2g[(size_t)(r*BB + b)*NN + i0 + t];
  __syncthreads();
  for (int idx = t; idx < 512; idx += 256){
    int rr = idx >> 6, c = idx & 63;
    float v = f[((size_t)(r*BB + b)*NN + i0 + rr)*CC + c];
    if (!euc) v *= 1.0f / fmaxf(sqrtf(yn2[rr]), 1e-12f);
    yl[rr][c] = v;
  }
  __syncthreads();

  const float* xs = (s==0)?x1:((s==1)?x2:x3);
  const float* colD = euc ? (xs + (size_t)(b*CC)*NN) : (fnT + (size_t)((s*BB + b)*CC)*NN);
  int j4 = 4*t;

  float ad[8][4];
  #pragma unroll
  for (int rr=0;rr<8;rr++){ ad[rr][0]=0.f; ad[rr][1]=0.f; ad[rr][2]=0.f; ad[rr][3]=0.f; }
  GEMM_COLS(8, colD, yl, j4, ad)

  float4 cn2 = make_float4(0.f,0.f,0.f,0.f);
  if (euc) cn2 = ld4(nrm2g + (size_t)(s*BB + b)*NN + j4);

  float sd = 0.f, sd2 = 0.f;
  #pragma unroll
  for (int rr=0;rr<8;rr++){
    float dv[4];
    DFINISH(euc, yn2[rr], cn2, ad[rr], dv)
    sd  += dv[0]+dv[1]+dv[2]+dv[3];
    sd2 += dv[0]*dv[0]+dv[1]*dv[1]+dv[2]*dv[2]+dv[3]*dv[3];
    float4 o4; o4.x=dv[0]; o4.y=dv[1]; o4.z=dv[2]; o4.w=dv[3];
    *reinterpret_cast<float4*>(&Dt[rr][j4]) = o4;
  }
  sd = wsum(sd); sd2 = wsum(sd2);
  if (lane == 0){ s1s[w] = sd; s2s[w] = sd2; }
  __syncthreads();                 // publishes Dt + s1s/s2s
  if (t == 0){
    double S  = (double)s1s[0] + (double)s1s[1] + (double)s1s[2] + (double)s1s[3];
    double S2 = (double)s2s[0] + (double)s2s[1] + (double)s2s[2] + (double)s2s[3];
    atomicAdd(&sums[m*2 + 0], S);
    atomicAdd(&sums[m*2 + 1], S2);
  }

  // ---- per-wave selection: wave w handles rows 2w, 2w+1; wave-private, barrier-free ----
  for (int rr2 = 0; rr2 < 2; rr2++){
    int row = w*2 + rr2;
    float dreg[16];
    #pragma unroll
    for (int k2=0;k2<4;k2++){
      float4 v = ld4(&Dt[row][4*lane + 256*k2]);
      dreg[4*k2+0]=v.x; dreg[4*k2+1]=v.y; dreg[4*k2+2]=v.z; dreg[4*k2+3]=v.w;
    }
    float lmin = 3.4e38f, lmax = -3.4e38f;
    #pragma unroll
    for (int k=0;k<16;k++){ lmin = fminf(lmin,dreg[k]); lmax = fmaxf(lmax,dreg[k]); }
    float Dmin = wminr(lmin);
    float Dmax = wmaxr(lmax);
    float lz = 0.f;
    #pragma unroll
    for (int k=0;k<16;k++) lz += expf((Dmin - dreg[k])*0.1f);
    float Z = wsum(lz);
    float invZ = 1.0f/Z;
    float preg[16];
    #pragma unroll
    for (int k=0;k<16;k++) preg[k] = expf((Dmin - dreg[k])*0.1f)*invZ;
    float le = 0.f;
    #pragma unroll
    for (int k=0;k<16;k++) le += preg[k]*logf(preg[k] + 1e-8f);
    float ent = -wsum(le);
    float decay = expf(-ent);
    float range = Dmax - Dmin;
    float scale1 = 256.0f / fmaxf(range, 1e-30f);

    if (lane==0){ selI4[w]=255; selC4[w]=0.8f; cnt4[w]=0; }
    #pragma unroll
    for (int i=0;i<4;i++) hist[w][lane*4+i] = 0.f;
    WVB();
    #pragma unroll
    for (int k=0;k<16;k++){
      int b1 = (int)((dreg[k]-Dmin)*scale1); b1 = (b1>255)?255:b1;
      atomicAdd(&hist[w][b1], preg[k]);
    }
    WVB();
    {
      float h0=hist[w][lane*4+0], h1=hist[w][lane*4+1], h2=hist[w][lane*4+2], h3=hist[w][lane*4+3];
      float tot = h0+h1+h2+h3;
      float incl = tot;
      #pragma unroll
      for (int o=1;o<64;o<<=1){ float v = __shfl_up(incl,o); if (lane>=o) incl += v; }
      float excl = incl - tot;
      float c0=excl, c1=excl+h0, c2=c1+h1, c3=c2+h2;
      bool f0=(c0<=0.8f && 0.8f<c0+h0), f1=(c1<=0.8f && 0.8f<c1+h1),
           f2=(c2<=0.8f && 0.8f<c2+h2), f3=(c3<=0.8f && 0.8f<c3+h3);
      if (f0){ selI4[w]=lane*4+0; selC4[w]=c0; }
      if (f1){ selI4[w]=lane*4+1; selC4[w]=c1; }
      if (f2){ selI4[w]=lane*4+2; selC4[w]=c2; }
      if (f3){ selI4[w]=lane*4+3; selC4[w]=c3; }
      if (__ballot(f0||f1||f2||f3) == 0ull){   // crack fallback
        int bi = 10000; float bc = 0.f;
        if (c0>0.8f){bi=lane*4+0;bc=c0;} else if (c1>0.8f){bi=lane*4+1;bc=c1;}
        else if (c2>0.8f){bi=lane*4+2;bc=c2;} else if (c3>0.8f){bi=lane*4+3;bc=c3;}
        int mn = bi;
        #pragma unroll
        for (int o=32;o;o>>=1) mn = min(mn, __shfl_xor(mn,o));
        if (mn==bi && bi<10000){ selI4[w]=bi; selC4[w]=bc; }
      }
    }
    WVB();
    int B1 = selI4[w]; float cb1 = selC4[w];
    float lo2 = Dmin + (float)B1/scale1;
    float scale2 = scale1*256.0f;
    if (lane==0){ selI4[w]=255; selC4[w]=cb1; }
    #pragma unroll
    for (int i=0;i<4;i++) hist[w][lane*4+i] = 0.f;
    WVB();
    #pragma unroll
    for (int k=0;k<16;k++){
      int b1 = (int)((dreg[k]-Dmin)*scale1); b1 = (b1>255)?255:b1;
      if (b1 == B1){
        int b2 = (int)((dreg[k]-lo2)*scale2); b2 = (b2<0)?0:((b2>255)?255:b2);
        atomicAdd(&hist[w][b2], preg[k]);
      }
    }
    WVB();
    {
      float h0=hist[w][lane*4+0], h1=hist[w][lane*4+1], h2=hist[w][lane*4+2], h3=hist[w][lane*4+3];
      float tot = h0+h1+h2+h3;
      float incl = tot;
      #pragma unroll
      for (int o=1;o<64;o<<=1){ float v = __shfl_up(incl,o); if (lane>=o) incl += v; }
      float excl = incl - tot;
      float c0=cb1+excl, c1=c0+h0, c2=c1+h1, c3=c2+h2;
      bool f0=(c0<=0.8f && 0.8f<c0+h0), f1=(c1<=0.8f && 0.8f<c1+h1),
           f2=(c2<=0.8f && 0.8f<c2+h2), f3=(c3<=0.8f && 0.8f<c3+h3);
      if (f0){ selI4[w]=lane*4+0; selC4[w]=c0; }
      if (f1){ selI4[w]=lane*4+1; selC4[w]=c1; }
      if (f2){ selI4[w]=lane*4+2; selC4[w]=c2; }
      if (f3){ selI4[w]=lane*4+3; selC4[w]=c3; }
      if (__ballot(f0||f1||f2||f3) == 0ull){
        int bi = 10000; float bc = 0.f;
        if (c0>0.8f){bi=lane*4+0;bc=c0;} else if (c1>0.8f){bi=lane*4+1;bc=c1;}
        else if (c2>0.8f){bi=lane*4+2;bc=c2;} else if (c3>0.8f){bi=lane*4+3;bc=c3;}
        int mn = bi;
        #pragma unroll
        for (int o=32;o;o>>=1) mn = min(mn, __shfl_xor(mn,o));
        if (mn==bi && bi<10000){ selI4[w]=bi; selC4[w]=bc; }
      }
    }
    WVB();
    int B2 = selI4[w]; float cb2 = selC4[w];

    // candidates in (B1,B2)
    #pragma unroll
    for (int k=0;k<16;k++){
      int b1 = (int)((dreg[k]-Dmin)*scale1); b1 = (b1>255)?255:b1;
      if (b1 == B1){
        int b2 = (int)((dreg[k]-lo2)*scale2); b2 = (b2<0)?0:((b2>255)?255:b2);
        if (b2 == B2){
          int c = atomicAdd(&cnt4[w], 1);
          if (c < 64){
            int j = (k>>2)*256 + 4*lane + (k&3);
            candj[w][c] = j;
            candd[w][c] = dreg[k];
            candb[w][c] = monob(dreg[k]);
          }
        }
      }
    }
    WVB();
    // lex-max element strictly before sub-bucket (B1,B2) — all selected
    ull em = 0;
    #pragma unroll
    for (int k=0;k<16;k++){
      int b1 = (int)((dreg[k]-Dmin)*scale1); b1 = (b1>255)?255:b1;
      bool qual;
      if (b1 < B1) qual = true;
      else if (b1 > B1) qual = false;
      else {
        int b2 = (int)((dreg[k]-lo2)*scale2); b2 = (b2<0)?0:((b2>255)?255:b2);
        qual = (b2 < B2);
      }
      if (qual){
        int j = (k>>2)*256 + 4*lane + (k&3);
        ull key = ((ull)monob(dreg[k]) << 32) | (u32)j;
        if (key > em) em = key;
      }
    }
    em = wmaxu64(em);
    if (lane == 0){
      int n = cnt4[w]; n = (n>64)?64:n;
      ull best = em;
      for (int a=0;a<n;a++){
        float da = candd[w][a]; int ja = candj[w][a];
        float acc = cb2;
        for (int bb=0;bb<n;bb++){
          float db = candd[w][bb]; int jb = candj[w][bb];
          if (db < da || (db == da && jb <= ja))
            acc += expf((Dmin - db)*0.1f)*invZ;
        }
        if (acc <= 0.8f){
          ull key = ((ull)candb[w][a] << 32) | (u32)ja;
          if (key > best) best = key;
        }
      }
      rec[(size_t)m*NN + i0 + row] = make_uint4((u32)(best>>32), (u32)(best & 0xFFFFFFFFu),
                                               __float_as_uint(Dmax), __float_as_uint(decay));
    }
    WVB();
  }
}

// ---------------- kapp: fused D+S GEMM + mask + softmax + o-accum ----------------
__global__ __launch_bounds__(256, 3)
void kapp(const float* __restrict__ x1, const float* __restrict__ x2, const float* __restrict__ x3,
          const float* __restrict__ f, const float* __restrict__ p,
          const float* __restrict__ fnT, const float* __restrict__ pT,
          const float* __restrict__ nrm2g, const float* __restrict__ baseg,
          const uint4* __restrict__ rec, float* __restrict__ out){
  __shared__ __align__(16) float yl[8][64];
  __shared__ __align__(16) float pyl[8][64];
  __shared__ __align__(16) float Sm[8][NN];        // 32KB
  __shared__ __align__(16) float opart[4][8][64];  // 8KB
  __shared__ float yn2[8];
  __shared__ u32 dBb[8]; __shared__ u32 jBl[8];
  __shared__ float th[8];

  int bid = blockIdx.x;
  int tile = bid & 127;            // 128 tiles of 8 rows
  int q = (bid >> 7) % 9;
  int b = bid / 1152;
  int r = q / 3, s = q - 3*r;
  bool euc = (r == s);
  int m = b*9 + q;
  int i0 = tile*8;
  int t = threadIdx.x;
  int w = t >> 6, lane = t & 63;

  if (t < 8){
    yn2[t] = nrm2g[(size_t)(r*BB + b)*NN + i0 + t];
    uint4 R = rec[(size_t)m*NN + i0 + t];
    dBb[t] = R.x; jBl[t] = R.y;
    float Dmax = __uint_as_float(R.z);
    float decay = __uint_as_float(R.w);
    float Tb = baseg[m];
    th[t] = (Tb + 0.01f*decay) / (1.0f + 0.01f*decay/Dmax);
  }
  __syncthreads();
  for (int idx = t; idx < 512; idx += 256){
    int rr = idx >> 6, c = idx & 63;
    float v = f[((size_t)(r*BB + b)*NN + i0 + rr)*CC + c];
    if (!euc) v *= 1.0f / fmaxf(sqrtf(yn2[rr]), 1e-12f);
    yl[rr][c] = v;
    pyl[rr][c] = p[((size_t)(r*BB + b)*NN + i0 + rr)*CC + c];
  }
  __syncthreads();

  const float* xs = (s==0)?x1:((s==1)?x2:x3);
  const float* colD = euc ? (xs + (size_t)(b*CC)*NN) : (fnT + (size_t)((s*BB + b)*CC)*NN);
  const float* colP = pT + (size_t)((s*BB + b)*CC)*NN;
  int j4 = 4*t;

  float ad[8][4];
  #pragma unroll
  for (int rr=0;rr<8;rr++){ ad[rr][0]=0.f; ad[rr][1]=0.f; ad[rr][2]=0.f; ad[rr][3]=0.f; }
  GEMM_COLS(8, colD, yl, j4, ad)

  float ap[8][4];
  #pragma unroll
  for (int rr=0;rr<8;rr++){ ap[rr][0]=0.f; ap[rr][1]=0.f; ap[rr][2]=0.f; ap[rr][3]=0.f; }
  GEMM_COLS(8, colP, pyl, j4, ap)

  float4 cn2 = make_float4(0.f,0.f,0.f,0.f);
  if (euc) cn2 = ld4(nrm2g + (size_t)(s*BB + b)*NN + j4);

  #pragma unroll
  for (int rr=0;rr<8;rr++){
    float dv[4];
    DFINISH(euc, yn2[rr], cn2, ad[rr], dv)
    u32 db = dBb[rr]; u32 jb = jBl[rr]; float tt = th[rr];
    float4 sv;
    {
      u32 bits = monob(dv[0]); u32 j = (u32)(j4+0);
      bool sel = (bits < db) || (bits == db && j <= jb);
      sv.x = (sel && dv[0] < tt) ? ap[rr][0] : 0.f;
    }
    {
      u32 bits = monob(dv[1]); u32 j = (u32)(j4+1);
      bool sel = (bits < db) || (bits == db && j <= jb);
      sv.y = (sel && dv[1] < tt) ? ap[rr][1] : 0.f;
    }
    {
      u32 bits = monob(dv[2]); u32 j = (u32)(j4+2);
      bool sel = (bits < db) || (bits == db && j <= jb);
      sv.z = (sel && dv[2] < tt) ? ap[rr][2] : 0.f;
    }
    {
      u32 bits = monob(dv[3]); u32 j = (u32)(j4+3);
      bool sel = (bits < db) || (bits == db && j <= jb);
      sv.w = (sel && dv[3] < tt) ? ap[rr][3] : 0.f;
    }
    *reinterpret_cast<float4*>(&Sm[rr][j4]) = sv;
  }
  __syncthreads();

  // row softmax: wave w owns rows 2w, 2w+1
  #pragma unroll
  for (int e=0;e<2;e++){
    int row = 2*w + e;
    float s16[16];
    #pragma unroll
    for (int k2=0;k2<4;k2++){
      float4 v = ld4(&Sm[row][4*lane + 256*k2]);
      s16[4*k2+0]=v.x; s16[4*k2+1]=v.y; s16[4*k2+2]=v.z; s16[4*k2+3]=v.w;
    }
    float lm = -3.4e38f;
    #pragma unroll
    for (int k=0;k<16;k++) lm = fmaxf(lm, s16[k]);
    float M = wmaxr(lm);
    float ls = 0.f;
    #pragma unroll
    for (int k=0;k<16;k++) ls += expf(s16[k]-M);
    float Z2 = wsum(ls);
    float iZ2 = 1.0f/Z2;
    #pragma unroll
    for (int k2=0;k2<4;k2++){
      float4 v;
      v.x = expf(s16[4*k2+0]-M)*iZ2;
      v.y = expf(s16[4*k2+1]-M)*iZ2;
      v.z = expf(s16[4*k2+2]-M)*iZ2;
      v.w = expf(s16[4*k2+3]-M)*iZ2;
      *reinterpret_cast<float4*>(&Sm[row][4*lane + 256*k2]) = v;
    }
  }
  __syncthreads();

  // o-accum: thread (cg = t&15 channel-quad, jj = t>>4), j = jj + 16*mm
  int cg = t & 15, jj = t >> 4;
  float acc[8][4];
  #pragma unroll
  for (int rr=0;rr<8;rr++){ acc[rr][0]=0.f; acc[rr][1]=0.f; acc[rr][2]=0.f; acc[rr][3]=0.f; }
  const float* fs = f + (size_t)((s*BB + b)*NN)*CC;
  for (int mm=0; mm<64; mm++){
    int j = jj + 16*mm;
    float4 fv = ld4(&fs[(size_t)j*CC + 4*cg]);
    #pragma unroll
    for (int rr=0;rr<8;rr++){
      float pv = Sm[rr][j];
      acc[rr][0] = fmaf(pv, fv.x, acc[rr][0]);
      acc[rr][1] = fmaf(pv, fv.y, acc[rr][1]);
      acc[rr][2] = fmaf(pv, fv.z, acc[rr][2]);
      acc[rr][3] = fmaf(pv, fv.w, acc[rr][3]);
    }
  }
  #pragma unroll
  for (int rr=0;rr<8;rr++){
    #pragma unroll
    for (int i=0;i<4;i++){
      acc[rr][i] += __shfl_xor(acc[rr][i], 16);
      acc[rr][i] += __shfl_xor(acc[rr][i], 32);
    }
  }
  if (lane < 16){
    #pragma unroll
    for (int rr=0;rr<8;rr++){
      float4 v; v.x=acc[rr][0]; v.y=acc[rr][1]; v.z=acc[rr][2]; v.w=acc[rr][3];
      *reinterpret_cast<float4*>(&opart[w][rr][4*cg]) = v;
    }
  }
  __syncthreads();
  #pragma unroll
  for (int e=0;e<2;e++){
    int idx = t + 256*e;
    int rr = idx >> 6, c = idx & 63;
    float v = opart[0][rr][c]+opart[1][rr][c]+opart[2][rr][c]+opart[3][rr][c];
    atomicAdd(&out[(size_t)(b*CC + c)*NN + i0 + rr], v);
  }
}

extern "C" void kernel_launch(void* const* d_in, const int* in_sizes, int n_in,
                              void* d_out, int out_size, void* d_ws, size_t ws_size,
                              hipStream_t stream){
  const float* x1 = (const float*)d_in[0];
  const float* x2 = (const float*)d_in[1];
  const float* x3 = (const float*)d_in[2];
  const float* w1 = (const float*)d_in[3];
  const float* b1 = (const float*)d_in[4];
  const float* w2 = (const float*)d_in[5];
  const float* b2 = (const float*)d_in[6];
  const float* w3 = (const float*)d_in[7];
  const float* b3 = (const float*)d_in[8];

  char* ws = (char*)d_ws;
  const size_t SZ = (size_t)3*BB*NN*CC*sizeof(float);   // 1.5MB each
  float*  f    = (float*)(ws);
  float*  p    = (float*)(ws + SZ);
  float*  fnT  = (float*)(ws + 2*SZ);
  float*  pT   = (float*)(ws + 3*SZ);
  float*  nrm2 = (float*)(ws + 4*SZ);
  double* sums = (double*)(ws + 4*SZ + 32768);
  float*  baseg= (float*)(ws + 4*SZ + 32768 + 512);
  uint4*  rec  = (uint4*)(ws + 4*SZ + 65536);           // 18*1024*16B = 288KB

  float* out = (float*)d_out;

  kz  <<<512, 256, 0, stream>>>(out, sums);
  k0a <<<96,  256, 0, stream>>>(x1, x2, x3, f);
  k0b <<<384, 256, 0, stream>>>(f, w1, b1, w2, b2, w3, b3, p, pT, fnT, nrm2);
  ksel<<<2304,256, 0, stream>>>(x1, x2, x3, f, fnT, nrm2, sums, rec);
  k2  <<<1,   64,  0, stream>>>(sums, baseg);
  kapp<<<2304,256, 0, stream>>>(x1, x2, x3, f, p, fnT, pT, nrm2, baseg, rec, out);
}

// Round 9
// 387.158 us; speedup vs baseline: 15.8780x; 1.0060x over previous
//
#include <hip/hip_runtime.h>

#define NN 1024
#define CC 64
#define BB 2

typedef unsigned long long ull;
typedef unsigned int u32;

#define WVB() __builtin_amdgcn_wave_barrier()

__device__ __forceinline__ float wsum(float v){
  #pragma unroll
  for (int o=32;o;o>>=1) v += __shfl_xor(v,o);
  return v;
}
__device__ __forceinline__ float wmaxr(float v){
  #pragma unroll
  for (int o=32;o;o>>=1) v = fmaxf(v, __shfl_xor(v,o));
  return v;
}
__device__ __forceinline__ float wminr(float v){
  #pragma unroll
  for (int o=32;o;o>>=1) v = fminf(v, __shfl_xor(v,o));
  return v;
}
__device__ __forceinline__ ull wmaxu64(ull v){
  #pragma unroll
  for (int o=32;o;o>>=1){ ull x = __shfl_xor(v,o); v = (x>v)?x:v; }
  return v;
}
__device__ __forceinline__ float4 ld4(const float* p){ return *reinterpret_cast<const float4*>(p); }
__device__ __forceinline__ u32 monob(float d){
  u32 u = __float_as_uint(d);
  return (u & 0x80000000u) ? ~u : (u | 0x80000000u);
}

// GEMM inner loop. "unroll 4" (NOT full unroll) is load-bearing: full unroll let
// the scheduler hoist all 64 column loads -> live range explosion -> accumulators
// spilled to scratch (R5/R6: 11-16GB HBM traffic, VALUBusy 2%, VGPR 84). R3/R7/R8
// used unroll 4 and stayed in registers. Identical text in ksel & kapp keeps the
// per-row fmaf chain bitwise-identical so the exact d==dB boundary test is valid.
#define GEMM_COLS(R, col, ylm, j4v, adv)                                          \
  { _Pragma("unroll 4")                                                           \
    for (int cc=0; cc<16; cc++){                                                  \
      float4 c0 = ld4((col) + (size_t)(cc*4+0)*NN + (j4v));                       \
      float4 c1 = ld4((col) + (size_t)(cc*4+1)*NN + (j4v));                       \
      float4 c2 = ld4((col) + (size_t)(cc*4+2)*NN + (j4v));                       \
      float4 c3 = ld4((col) + (size_t)(cc*4+3)*NN + (j4v));                       \
      _Pragma("unroll")                                                           \
      for (int rr=0; rr<(R); rr++){                                               \
        float4 y4 = *reinterpret_cast<const float4*>(&(ylm)[rr][cc*4]);           \
        float a0 = adv[rr][0], a1 = adv[rr][1], a2 = adv[rr][2], a3 = adv[rr][3]; \
        a0 = fmaf(y4.x,c0.x,a0); a0 = fmaf(y4.y,c1.x,a0); a0 = fmaf(y4.z,c2.x,a0); a0 = fmaf(y4.w,c3.x,a0); \
        a1 = fmaf(y4.x,c0.y,a1); a1 = fmaf(y4.y,c1.y,a1); a1 = fmaf(y4.z,c2.y,a1); a1 = fmaf(y4.w,c3.y,a1); \
        a2 = fmaf(y4.x,c0.z,a2); a2 = fmaf(y4.y,c1.z,a2); a2 = fmaf(y4.z,c2.z,a2); a2 = fmaf(y4.w,c3.z,a2); \
        a3 = fmaf(y4.x,c0.w,a3); a3 = fmaf(y4.y,c1.w,a3); a3 = fmaf(y4.z,c2.w,a3); a3 = fmaf(y4.w,c3.w,a3); \
        adv[rr][0]=a0; adv[rr][1]=a1; adv[rr][2]=a2; adv[rr][3]=a3;               \
      }                                                                           \
    }                                                                             \
  }

// D epilogue macro — identical value chain in both kernels.
#define DFINISH(eucv, yn2r, cn2v, adr, dvv)                                       \
  { if (eucv){                                                                    \
      dvv[0] = sqrtf(fmaxf(fmaf(-2.0f, adr[0], (yn2r) + (cn2v).x), 1e-12f));      \
      dvv[1] = sqrtf(fmaxf(fmaf(-2.0f, adr[1], (yn2r) + (cn2v).y), 1e-12f));      \
      dvv[2] = sqrtf(fmaxf(fmaf(-2.0f, adr[2], (yn2r) + (cn2v).z), 1e-12f));      \
      dvv[3] = sqrtf(fmaxf(fmaf(-2.0f, adr[3], (yn2r) + (cn2v).w), 1e-12f));      \
    } else {                                                                      \
      dvv[0] = 1.0f - adr[0]; dvv[1] = 1.0f - adr[1];                             \
      dvv[2] = 1.0f - adr[2]; dvv[3] = 1.0f - adr[3];                             \
    }                                                                             \
  }

#define BUCKET1(dv) ({ int _b = (int)(((dv)-Dmin)*scale1); (_b>255)?255:_b; })

// ---------------- zero init ----------------
__global__ void kz(float* __restrict__ out, double* __restrict__ sums){
  int i = blockIdx.x*256 + threadIdx.x;
  if (i < BB*CC*NN) out[i] = 0.0f;
  if (i < 36) sums[i] = 0.0;
}

// ---------------- K0a: transpose x[b][c][n] -> f[s][b][n][c] ----------------
__global__ __launch_bounds__(256)
void k0a(const float* __restrict__ x1, const float* __restrict__ x2, const float* __restrict__ x3,
         float* __restrict__ f){
  int bid = blockIdx.x;
  int tile = bid & 15;
  int b = (bid >> 4) & 1;
  int s = bid >> 5;
  const float* x = (s==0)?x1:((s==1)?x2:x3);
  __shared__ float lds[64][65];
  int i0 = tile*64;
  for (int idx = threadIdx.x; idx < 4096; idx += 256){
    int c = idx >> 6, ii = idx & 63;
    lds[c][ii] = x[(size_t)(b*CC + c)*NN + i0 + ii];
  }
  __syncthreads();
  for (int idx = threadIdx.x; idx < 4096; idx += 256){
    int ii = idx >> 6, c = idx & 63;
    f[((size_t)(s*BB + b)*NN + i0 + ii)*CC + c] = lds[c][ii];
  }
}

// ---------------- K0b: norms, fnT, p, pT ----------------
__global__ __launch_bounds__(256)
void k0b(const float* __restrict__ f,
         const float* __restrict__ w1, const float* __restrict__ b1,
         const float* __restrict__ w2, const float* __restrict__ b2,
         const float* __restrict__ w3, const float* __restrict__ b3,
         float* __restrict__ p, float* __restrict__ pT,
         float* __restrict__ fnT, float* __restrict__ nrm2g){
  int bid = blockIdx.x;
  int chunk = bid & 63;
  int b = (bid >> 6) & 1;
  int s = bid >> 7;
  const float* w = (s==0)?w1:((s==1)?w2:w3);
  const float* bias = (s==0)?b1:((s==1)?b2:b3);
  __shared__ float wl[64][65];
  __shared__ float fr[16][65];
  __shared__ float n2[16];
  int i0 = chunk*16;
  int t = threadIdx.x;
  for (int idx = t; idx < 4096; idx += 256){
    int o = idx >> 6, c = idx & 63;
    wl[o][c] = w[idx];
  }
  for (int idx = t; idx < 1024; idx += 256){
    int rr = idx >> 6, c = idx & 63;
    fr[rr][c] = f[((size_t)(s*BB + b)*NN + i0 + rr)*CC + c];
  }
  __syncthreads();
  {
    int r = t >> 4, l = t & 15;
    float pv = 0.f;
    for (int c = l; c < 64; c += 16) pv += fr[r][c]*fr[r][c];
    #pragma unroll
    for (int o=8;o;o>>=1) pv += __shfl_down(pv, o, 16);
    if (l == 0) n2[r] = pv;
  }
  __syncthreads();
  if (t < 16) nrm2g[(size_t)(s*BB + b)*NN + i0 + t] = n2[t];
  for (int idx = t; idx < 1024; idx += 256){
    int rr = idx >> 6, c = idx & 63;
    float rinv = 1.0f / fmaxf(sqrtf(n2[rr]), 1e-12f);
    fnT[((size_t)(s*BB + b)*CC + c)*NN + i0 + rr] = fr[rr][c]*rinv;
  }
  for (int idx = t; idx < 1024; idx += 256){
    int rr = idx >> 6, o = idx & 63;
    float acc = bias[o];
    #pragma unroll
    for (int c = 0; c < 64; c++) acc += fr[rr][c]*wl[o][c];
    p [((size_t)(s*BB + b)*NN + i0 + rr)*CC + o] = acc;
    pT[((size_t)(s*BB + b)*CC + o)*NN + i0 + rr] = acc;
  }
}

// ---------------- K2: mu + alpha*sigma ----------------
__global__ void k2(const double* __restrict__ sums, float* __restrict__ baseg){
  int t = threadIdx.x;
  if (t < 18){
    double S = sums[t*2], S2 = sums[t*2+1];
    const double Nsq = 1048576.0;
    double mu = S / Nsq;
    double var = (S2 - S*S/Nsq) / (Nsq - 1.0);
    double sg = var > 0.0 ? sqrt(var) : 0.0;
    baseg[t] = (float)(mu + 0.08*sg);
  }
}

// ---------------- ksel: D-GEMM + stats + per-row selection boundary ----------------
// Selection (R9): exp-reuse, log-free decay = exp(sum p*logit)/Z, level-2 only if
// boundary bucket holds >64 elems, and PARALLEL candidate resolve (lane l resolves
// candidate l) replacing R8's serial lane-0 n^2 walk.
// rec[m*NN+i] = {dB_bits, jB, Dmax_bits, decay_bits}; selected(j) <=> (bits<dB)||(bits==dB && j<=jB)
__global__ __launch_bounds__(256, 3)
void ksel(const float* __restrict__ x1, const float* __restrict__ x2, const float* __restrict__ x3,
          const float* __restrict__ f, const float* __restrict__ fnT,
          const float* __restrict__ nrm2g, double* __restrict__ sums, uint4* __restrict__ rec){
  __shared__ __align__(16) float yl[8][64];      // 2KB
  __shared__ __align__(16) float Dt[8][NN];      // 32KB
  __shared__ float hist[4][256];                 // 4KB
  __shared__ float candp[4][64];
  __shared__ int   candj[4][64];
  __shared__ u32   candb[4][64];
  __shared__ float yn2[8];
  __shared__ int   cnt4[4];
  __shared__ int   selI4[4];
  __shared__ float selC4[4];
  __shared__ float s1s[4], s2s[4];

  int bid = blockIdx.x;
  int tile = bid & 127;            // 128 tiles of 8 rows
  int q = (bid >> 7) % 9;
  int b = bid / 1152;
  int r = q / 3, s = q - 3*r;
  bool euc = (r == s);
  int m = b*9 + q;
  int i0 = tile*8;
  int t = threadIdx.x;
  int w = t >> 6, lane = t & 63;

  if (t < 8) yn2[t] = nrm2g[(size_t)(r*BB + b)*NN + i0 + t];
  __syncthreads();
  for (int idx = t; idx < 512; idx += 256){
    int rr = idx >> 6, c = idx & 63;
    float v = f[((size_t)(r*BB + b)*NN + i0 + rr)*CC + c];
    if (!euc) v *= 1.0f / fmaxf(sqrtf(yn2[rr]), 1e-12f);
    yl[rr][c] = v;
  }
  __syncthreads();

  const float* xs = (s==0)?x1:((s==1)?x2:x3);
  const float* colD = euc ? (xs + (size_t)(b*CC)*NN) : (fnT + (size_t)((s*BB + b)*CC)*NN);
  int j4 = 4*t;

  float ad[8][4];
  #pragma unroll
  for (int rr=0;rr<8;rr++){ ad[rr][0]=0.f; ad[rr][1]=0.f; ad[rr][2]=0.f; ad[rr][3]=0.f; }
  GEMM_COLS(8, colD, yl, j4, ad)

  float4 cn2 = make_float4(0.f,0.f,0.f,0.f);
  if (euc) cn2 = ld4(nrm2g + (size_t)(s*BB + b)*NN + j4);

  float sd = 0.f, sd2 = 0.f;
  #pragma unroll
  for (int rr=0;rr<8;rr++){
    float dv[4];
    DFINISH(euc, yn2[rr], cn2, ad[rr], dv)
    sd  += dv[0]+dv[1]+dv[2]+dv[3];
    sd2 += dv[0]*dv[0]+dv[1]*dv[1]+dv[2]*dv[2]+dv[3]*dv[3];
    float4 o4; o4.x=dv[0]; o4.y=dv[1]; o4.z=dv[2]; o4.w=dv[3];
    *reinterpret_cast<float4*>(&Dt[rr][j4]) = o4;
  }
  sd = wsum(sd); sd2 = wsum(sd2);
  if (lane == 0){ s1s[w] = sd; s2s[w] = sd2; }
  __syncthreads();                 // publishes Dt + s1s/s2s
  if (t == 0){
    double S  = (double)s1s[0] + (double)s1s[1] + (double)s1s[2] + (double)s1s[3];
    double S2 = (double)s2s[0] + (double)s2s[1] + (double)s2s[2] + (double)s2s[3];
    atomicAdd(&sums[m*2 + 0], S);
    atomicAdd(&sums[m*2 + 1], S2);
  }

  // ---- per-wave selection: wave w handles rows 2w, 2w+1; wave-private, barrier-free ----
  for (int rr2 = 0; rr2 < 2; rr2++){
    int row = w*2 + rr2;
    float dreg[16];
    #pragma unroll
    for (int k2=0;k2<4;k2++){
      float4 v = ld4(&Dt[row][4*lane + 256*k2]);
      dreg[4*k2+0]=v.x; dreg[4*k2+1]=v.y; dreg[4*k2+2]=v.z; dreg[4*k2+3]=v.w;
    }
    float lmin = 3.4e38f, lmax = -3.4e38f;
    #pragma unroll
    for (int k=0;k<16;k++){ lmin = fminf(lmin,dreg[k]); lmax = fmaxf(lmax,dreg[k]); }
    float Dmin = wminr(lmin);
    float Dmax = wmaxr(lmax);
    // single exp pass; reuse for probs
    float preg[16];
    float lz = 0.f;
    #pragma unroll
    for (int k=0;k<16;k++){ preg[k] = expf((Dmin - dreg[k])*0.1f); lz += preg[k]; }
    float Z = wsum(lz);
    float invZ = 1.0f/Z;
    #pragma unroll
    for (int k=0;k<16;k++) preg[k] *= invZ;
    // log-free decay: ent = lnZ - sum(p*logit) -> decay = exp(sum(p*logit))/Z
    float sl = 0.f;
    #pragma unroll
    for (int k=0;k<16;k++) sl = fmaf(preg[k], (Dmin - dreg[k])*0.1f, sl);
    float sumpl = wsum(sl);
    float decay = expf(sumpl)*invZ;
    float range = Dmax - Dmin;
    float scale1 = 256.0f / fmaxf(range, 1e-30f);

    // ---- level-1 histogram ----
    if (lane==0){ selI4[w]=255; selC4[w]=0.8f; }
    #pragma unroll
    for (int i=0;i<4;i++) hist[w][lane*4+i] = 0.f;
    WVB();
    #pragma unroll
    for (int k=0;k<16;k++){
      int b1 = BUCKET1(dreg[k]);
      atomicAdd(&hist[w][b1], preg[k]);
    }
    WVB();
    {
      float h0=hist[w][lane*4+0], h1=hist[w][lane*4+1], h2=hist[w][lane*4+2], h3=hist[w][lane*4+3];
      float tot = h0+h1+h2+h3;
      float incl = tot;
      #pragma unroll
      for (int o=1;o<64;o<<=1){ float v = __shfl_up(incl,o); if (lane>=o) incl += v; }
      float excl = incl - tot;
      float c0=excl, c1=excl+h0, c2=c1+h1, c3=c2+h2;
      bool f0=(c0<=0.8f && 0.8f<c0+h0), f1=(c1<=0.8f && 0.8f<c1+h1),
           f2=(c2<=0.8f && 0.8f<c2+h2), f3=(c3<=0.8f && 0.8f<c3+h3);
      if (f0){ selI4[w]=lane*4+0; selC4[w]=c0; }
      if (f1){ selI4[w]=lane*4+1; selC4[w]=c1; }
      if (f2){ selI4[w]=lane*4+2; selC4[w]=c2; }
      if (f3){ selI4[w]=lane*4+3; selC4[w]=c3; }
      if (__ballot(f0||f1||f2||f3) == 0ull){   // crack fallback
        int bi = 10000; float bc = 0.f;
        if (c0>0.8f){bi=lane*4+0;bc=c0;} else if (c1>0.8f){bi=lane*4+1;bc=c1;}
        else if (c2>0.8f){bi=lane*4+2;bc=c2;} else if (c3>0.8f){bi=lane*4+3;bc=c3;}
        int mn = bi;
        #pragma unroll
        for (int o=32;o;o>>=1) mn = min(mn, __shfl_xor(mn,o));
        if (mn==bi && bi<10000){ selI4[w]=bi; selC4[w]=bc; }
      }
    }
    WVB();
    int B1 = selI4[w]; float cb1 = selC4[w];

    // ---- count boundary-bucket population; level-2 only if > 64 ----
    float cntf = 0.f;
    #pragma unroll
    for (int k=0;k<16;k++) if (BUCKET1(dreg[k]) == B1) cntf += 1.0f;
    float n1f = wsum(cntf);
    bool need2 = (n1f > 64.0f);
    float cb = cb1;
    int B2 = 0; float lo2 = 0.f, scale2 = 0.f;
    if (need2){
      lo2 = Dmin + (float)B1/scale1;
      scale2 = scale1*256.0f;
      if (lane==0){ selI4[w]=255; selC4[w]=cb1; }
      #pragma unroll
      for (int i=0;i<4;i++) hist[w][lane*4+i] = 0.f;
      WVB();
      #pragma unroll
      for (int k=0;k<16;k++){
        if (BUCKET1(dreg[k]) == B1){
          int b2 = (int)((dreg[k]-lo2)*scale2); b2 = (b2<0)?0:((b2>255)?255:b2);
          atomicAdd(&hist[w][b2], preg[k]);
        }
      }
      WVB();
      {
        float h0=hist[w][lane*4+0], h1=hist[w][lane*4+1], h2=hist[w][lane*4+2], h3=hist[w][lane*4+3];
        float tot = h0+h1+h2+h3;
        float incl = tot;
        #pragma unroll
        for (int o=1;o<64;o<<=1){ float v = __shfl_up(incl,o); if (lane>=o) incl += v; }
        float excl = incl - tot;
        float c0=cb1+excl, c1=c0+h0, c2=c1+h1, c3=c2+h2;
        bool f0=(c0<=0.8f && 0.8f<c0+h0), f1=(c1<=0.8f && 0.8f<c1+h1),
             f2=(c2<=0.8f && 0.8f<c2+h2), f3=(c3<=0.8f && 0.8f<c3+h3);
        if (f0){ selI4[w]=lane*4+0; selC4[w]=c0; }
        if (f1){ selI4[w]=lane*4+1; selC4[w]=c1; }
        if (f2){ selI4[w]=lane*4+2; selC4[w]=c2; }
        if (f3){ selI4[w]=lane*4+3; selC4[w]=c3; }
        if (__ballot(f0||f1||f2||f3) == 0ull){
          int bi = 10000; float bc = 0.f;
          if (c0>0.8f){bi=lane*4+0;bc=c0;} else if (c1>0.8f){bi=lane*4+1;bc=c1;}
          else if (c2>0.8f){bi=lane*4+2;bc=c2;} else if (c3>0.8f){bi=lane*4+3;bc=c3;}
          int mn = bi;
          #pragma unroll
          for (int o=32;o;o>>=1) mn = min(mn, __shfl_xor(mn,o));
          if (mn==bi && bi<10000){ selI4[w]=bi; selC4[w]=bc; }
        }
      }
      WVB();
      B2 = selI4[w]; cb = selC4[w];
    }

    // ---- collect candidates ----
    if (lane==0) cnt4[w] = 0;
    WVB();
    #pragma unroll
    for (int k=0;k<16;k++){
      bool inb = (BUCKET1(dreg[k]) == B1);
      if (need2 && inb){
        int b2 = (int)((dreg[k]-lo2)*scale2); b2 = (b2<0)?0:((b2>255)?255:b2);
        inb = (b2 == B2);
      }
      if (inb){
        int c = atomicAdd(&cnt4[w], 1);
        if (c < 64){
          int j = (k>>2)*256 + 4*lane + (k&3);
          candj[w][c] = j;
          candb[w][c] = monob(dreg[k]);
          candp[w][c] = preg[k];
        }
      }
    }
    WVB();
    int n = cnt4[w]; n = (n>64)?64:n;

    // ---- parallel resolve: lane l resolves candidate l ----
    u32 myb = 0, myj = 0;
    if (lane < n){ myb = candb[w][lane]; myj = (u32)candj[w][lane]; }
    float acc = cb;
    for (int a=0;a<n;a++){
      u32 ba = candb[w][a]; u32 ja = (u32)candj[w][a]; float pa = candp[w][a];
      bool le = (ba < myb) || (ba == myb && ja <= myj);
      acc += le ? pa : 0.f;
    }
    // ---- boundary = lex-max of {strictly-before region} ∪ {selected candidates} ----
    ull em = 0;
    #pragma unroll
    for (int k=0;k<16;k++){
      int b1v = BUCKET1(dreg[k]);
      bool qual = (b1v < B1);
      if (need2 && b1v == B1){
        int b2 = (int)((dreg[k]-lo2)*scale2); b2 = (b2<0)?0:((b2>255)?255:b2);
        qual = (b2 < B2);
      }
      if (qual){
        int j = (k>>2)*256 + 4*lane + (k&3);
        ull key = ((ull)monob(dreg[k]) << 32) | (u32)j;
        if (key > em) em = key;
      }
    }
    if (lane < n && acc <= 0.8f){
      ull key = ((ull)myb << 32) | myj;
      if (key > em) em = key;
    }
    em = wmaxu64(em);
    if (lane == 0){
      rec[(size_t)m*NN + i0 + row] = make_uint4((u32)(em>>32), (u32)(em & 0xFFFFFFFFu),
                                               __float_as_uint(Dmax), __float_as_uint(decay));
    }
    WVB();
  }
}

// ---------------- kapp: fused D+S GEMM + mask + softmax + o-accum ----------------
__global__ __launch_bounds__(256, 3)
void kapp(const float* __restrict__ x1, const float* __restrict__ x2, const float* __restrict__ x3,
          const float* __restrict__ f, const float* __restrict__ p,
          const float* __restrict__ fnT, const float* __restrict__ pT,
          const float* __restrict__ nrm2g, const float* __restrict__ baseg,
          const uint4* __restrict__ rec, float* __restrict__ out){
  __shared__ __align__(16) float yl[8][64];
  __shared__ __align__(16) float pyl[8][64];
  __shared__ __align__(16) float Sm[8][NN];        // 32KB
  __shared__ __align__(16) float opart[4][8][64];  // 8KB
  __shared__ float yn2[8];
  __shared__ u32 dBb[8]; __shared__ u32 jBl[8];
  __shared__ float th[8];

  int bid = blockIdx.x;
  int tile = bid & 127;            // 128 tiles of 8 rows
  int q = (bid >> 7) % 9;
  int b = bid / 1152;
  int r = q / 3, s = q - 3*r;
  bool euc = (r == s);
  int m = b*9 + q;
  int i0 = tile*8;
  int t = threadIdx.x;
  int w = t >> 6, lane = t & 63;

  if (t < 8){
    yn2[t] = nrm2g[(size_t)(r*BB + b)*NN + i0 + t];
    uint4 R = rec[(size_t)m*NN + i0 + t];
    dBb[t] = R.x; jBl[t] = R.y;
    float Dmax = __uint_as_float(R.z);
    float decay = __uint_as_float(R.w);
    float Tb = baseg[m];
    th[t] = (Tb + 0.01f*decay) / (1.0f + 0.01f*decay/Dmax);
  }
  __syncthreads();
  for (int idx = t; idx < 512; idx += 256){
    int rr = idx >> 6, c = idx & 63;
    float v = f[((size_t)(r*BB + b)*NN + i0 + rr)*CC + c];
    if (!euc) v *= 1.0f / fmaxf(sqrtf(yn2[rr]), 1e-12f);
    yl[rr][c] = v;
    pyl[rr][c] = p[((size_t)(r*BB + b)*NN + i0 + rr)*CC + c];
  }
  __syncthreads();

  const float* xs = (s==0)?x1:((s==1)?x2:x3);
  const float* colD = euc ? (xs + (size_t)(b*CC)*NN) : (fnT + (size_t)((s*BB + b)*CC)*NN);
  const float* colP = pT + (size_t)((s*BB + b)*CC)*NN;
  int j4 = 4*t;

  float ad[8][4];
  #pragma unroll
  for (int rr=0;rr<8;rr++){ ad[rr][0]=0.f; ad[rr][1]=0.f; ad[rr][2]=0.f; ad[rr][3]=0.f; }
  GEMM_COLS(8, colD, yl, j4, ad)

  float ap[8][4];
  #pragma unroll
  for (int rr=0;rr<8;rr++){ ap[rr][0]=0.f; ap[rr][1]=0.f; ap[rr][2]=0.f; ap[rr][3]=0.f; }
  GEMM_COLS(8, colP, pyl, j4, ap)

  float4 cn2 = make_float4(0.f,0.f,0.f,0.f);
  if (euc) cn2 = ld4(nrm2g + (size_t)(s*BB + b)*NN + j4);

  #pragma unroll
  for (int rr=0;rr<8;rr++){
    float dv[4];
    DFINISH(euc, yn2[rr], cn2, ad[rr], dv)
    u32 db = dBb[rr]; u32 jb = jBl[rr]; float tt = th[rr];
    float4 sv;
    {
      u32 bits = monob(dv[0]); u32 j = (u32)(j4+0);
      bool sel = (bits < db) || (bits == db && j <= jb);
      sv.x = (sel && dv[0] < tt) ? ap[rr][0] : 0.f;
    }
    {
      u32 bits = monob(dv[1]); u32 j = (u32)(j4+1);
      bool sel = (bits < db) || (bits == db && j <= jb);
      sv.y = (sel && dv[1] < tt) ? ap[rr][1] : 0.f;
    }
    {
      u32 bits = monob(dv[2]); u32 j = (u32)(j4+2);
      bool sel = (bits < db) || (bits == db && j <= jb);
      sv.z = (sel && dv[2] < tt) ? ap[rr][2] : 0.f;
    }
    {
      u32 bits = monob(dv[3]); u32 j = (u32)(j4+3);
      bool sel = (bits < db) || (bits == db && j <= jb);
      sv.w = (sel && dv[3] < tt) ? ap[rr][3] : 0.f;
    }
    *reinterpret_cast<float4*>(&Sm[rr][j4]) = sv;
  }
  __syncthreads();

  // row softmax: wave w owns rows 2w, 2w+1 (exp computed once, reused for write)
  #pragma unroll
  for (int e=0;e<2;e++){
    int row = 2*w + e;
    float s16[16];
    #pragma unroll
    for (int k2=0;k2<4;k2++){
      float4 v = ld4(&Sm[row][4*lane + 256*k2]);
      s16[4*k2+0]=v.x; s16[4*k2+1]=v.y; s16[4*k2+2]=v.z; s16[4*k2+3]=v.w;
    }
    float lm = -3.4e38f;
    #pragma unroll
    for (int k=0;k<16;k++) lm = fmaxf(lm, s16[k]);
    float M = wmaxr(lm);
    float ls = 0.f;
    #pragma unroll
    for (int k=0;k<16;k++){ s16[k] = expf(s16[k]-M); ls += s16[k]; }
    float Z2 = wsum(ls);
    float iZ2 = 1.0f/Z2;
    #pragma unroll
    for (int k2=0;k2<4;k2++){
      float4 v;
      v.x = s16[4*k2+0]*iZ2;
      v.y = s16[4*k2+1]*iZ2;
      v.z = s16[4*k2+2]*iZ2;
      v.w = s16[4*k2+3]*iZ2;
      *reinterpret_cast<float4*>(&Sm[row][4*lane + 256*k2]) = v;
    }
  }
  __syncthreads();

  // o-accum: thread (cg = t&15 channel-quad, jj = t>>4), j = jj + 16*mm
  int cg = t & 15, jj = t >> 4;
  float acc[8][4];
  #pragma unroll
  for (int rr=0;rr<8;rr++){ acc[rr][0]=0.f; acc[rr][1]=0.f; acc[rr][2]=0.f; acc[rr][3]=0.f; }
  const float* fs = f + (size_t)((s*BB + b)*NN)*CC;
  for (int mm=0; mm<64; mm++){
    int j = jj + 16*mm;
    float4 fv = ld4(&fs[(size_t)j*CC + 4*cg]);
    #pragma unroll
    for (int rr=0;rr<8;rr++){
      float pv = Sm[rr][j];
      acc[rr][0] = fmaf(pv, fv.x, acc[rr][0]);
      acc[rr][1] = fmaf(pv, fv.y, acc[rr][1]);
      acc[rr][2] = fmaf(pv, fv.z, acc[rr][2]);
      acc[rr][3] = fmaf(pv, fv.w, acc[rr][3]);
    }
  }
  #pragma unroll
  for (int rr=0;rr<8;rr++){
    #pragma unroll
    for (int i=0;i<4;i++){
      acc[rr][i] += __shfl_xor(acc[rr][i], 16);
      acc[rr][i] += __shfl_xor(acc[rr][i], 32);
    }
  }
  if (lane < 16){
    #pragma unroll
    for (int rr=0;rr<8;rr++){
      float4 v; v.x=acc[rr][0]; v.y=acc[rr][1]; v.z=acc[rr][2]; v.w=acc[rr][3];
      *reinterpret_cast<float4*>(&opart[w][rr][4*cg]) = v;
    }
  }
  __syncthreads();
  #pragma unroll
  for (int e=0;e<2;e++){
    int idx = t + 256*e;
    int rr = idx >> 6, c = idx & 63;
    float v = opart[0][rr][c]+opart[1][rr][c]+opart[2][rr][c]+opart[3][rr][c];
    atomicAdd(&out[(size_t)(b*CC + c)*NN + i0 + rr], v);
  }
}

extern "C" void kernel_launch(void* const* d_in, const int* in_sizes, int n_in,
                              void* d_out, int out_size, void* d_ws, size_t ws_size,
                              hipStream_t stream){
  const float* x1 = (const float*)d_in[0];
  const float* x2 = (const float*)d_in[1];
  const float* x3 = (const float*)d_in[2];
  const float* w1 = (const float*)d_in[3];
  const float* b1 = (const float*)d_in[4];
  const float* w2 = (const float*)d_in[5];
  const float* b2 = (const float*)d_in[6];
  const float* w3 = (const float*)d_in[7];
  const float* b3 = (const float*)d_in[8];

  char* ws = (char*)d_ws;
  const size_t SZ = (size_t)3*BB*NN*CC*sizeof(float);   // 1.5MB each
  float*  f    = (float*)(ws);
  float*  p    = (float*)(ws + SZ);
  float*  fnT  = (float*)(ws + 2*SZ);
  float*  pT   = (float*)(ws + 3*SZ);
  float*  nrm2 = (float*)(ws + 4*SZ);
  double* sums = (double*)(ws + 4*SZ + 32768);
  float*  baseg= (float*)(ws + 4*SZ + 32768 + 512);
  uint4*  rec  = (uint4*)(ws + 4*SZ + 65536);           // 18*1024*16B = 288KB

  float* out = (float*)d_out;

  kz  <<<512, 256, 0, stream>>>(out, sums);
  k0a <<<96,  256, 0, stream>>>(x1, x2, x3, f);
  k0b <<<384, 256, 0, stream>>>(f, w1, b1, w2, b2, w3, b3, p, pT, fnT, nrm2);
  ksel<<<2304,256, 0, stream>>>(x1, x2, x3, f, fnT, nrm2, sums, rec);
  k2  <<<1,   64,  0, stream>>>(sums, baseg);
  kapp<<<2304,256, 0, stream>>>(x1, x2, x3, f, p, fnT, pT, nrm2, baseg, rec, out);
}